// Round 2
// baseline (900.869 us; speedup 1.0000x reference)
//
#include <hip/hip_runtime.h>
#include <hip/hip_bf16.h>

#define HID 128
#define NEG_SLOPE 0.2f
#define LN_EPS 1e-5f
#define SEG_CAP 8192   // max edges per 256-node bucket (mean 4096, sigma~64)

typedef __attribute__((ext_vector_type(8))) short short8;
typedef __attribute__((ext_vector_type(4))) float floatx4;

// ---------- helpers ----------
__device__ __forceinline__ float us2f(unsigned short u) {
    union { unsigned int i; float f; } c; c.i = ((unsigned int)u) << 16; return c.f;
}
__device__ __forceinline__ float lo2f(unsigned u) {
    union { unsigned int i; float f; } c; c.i = u << 16; return c.f;
}
__device__ __forceinline__ float hi2f(unsigned u) {
    union { unsigned int i; float f; } c; c.i = u & 0xffff0000u; return c.f;
}
__device__ __forceinline__ unsigned short f2us(float f) {  // RNE bf16 pack
    union { float f; unsigned u; } c; c.f = f;
    unsigned r = c.u + 0x7FFF + ((c.u >> 16) & 1);
    return (unsigned short)(r >> 16);
}
__device__ __forceinline__ unsigned pack2(float a, float b) {
    return (unsigned)f2us(a) | ((unsigned)f2us(b) << 16);
}
__device__ __forceinline__ float ldw(const void* p, long i, int bf) {
    return bf ? us2f(((const unsigned short*)p)[i]) : ((const float*)p)[i];
}
__device__ __forceinline__ float lrelu(float x) { return x > 0.f ? x : NEG_SLOPE * x; }
__device__ __forceinline__ float wsum(float x) {
#pragma unroll
    for (int o = 32; o > 0; o >>= 1) x += __shfl_xor(x, o);
    return x;
}
__device__ __forceinline__ float pick4(float4 v, int h) {
    return h == 0 ? v.x : (h == 1 ? v.y : (h == 2 ? v.z : v.w));
}

// ---------- dtype sniff ----------
__global__ void detect_kernel(const float* __restrict__ x, int* __restrict__ flag) {
    float v = x[threadIdx.x];
    int bad = (!(v == v)) || (fabsf(v) > 1e6f);
    unsigned long long m = __ballot(bad);
    if (threadIdx.x == 0) flag[0] = (m != 0ull) ? 1 : 0;
}

__global__ __launch_bounds__(256) void zero_int_kernel(int* p, int n) {
    int i = blockIdx.x * 256 + threadIdx.x;
    if (i < n) p[i] = 0;
}

// ---------- CSR build: bucket partition (256 dst-nodes per bucket) ----------
// K1: per-tile LDS histogram -> global bucket counts (few global atomics)
__global__ __launch_bounds__(256) void bucket_hist_kernel(const int* __restrict__ dst, int E, int nb,
                                                          int* __restrict__ bucket_cnt) {
    __shared__ int hist[512];
    for (int i = threadIdx.x; i < nb; i += 256) hist[i] = 0;
    __syncthreads();
    const int base = blockIdx.x * 4096;
    const int end = min(base + 4096, E);
    for (int i = base + threadIdx.x; i < end; i += 256)
        atomicAdd(&hist[dst[i] >> 8], 1);
    __syncthreads();
    for (int i = threadIdx.x; i < nb; i += 256)
        if (hist[i]) atomicAdd(&bucket_cnt[i], hist[i]);
}

// K2: scan bucket counts -> bucket_base (csr segment starts), init cursors, row_ptr[N]
__global__ __launch_bounds__(512) void bucket_scan_kernel(const int* __restrict__ bucket_cnt,
                                                          int* __restrict__ bucket_base,
                                                          int* __restrict__ cursor,
                                                          int nb, int* __restrict__ row_ptr, int N) {
    __shared__ int sc[512];
    const int t = threadIdx.x;
    const int v = (t < nb) ? bucket_cnt[t] : 0;
    int x = v;
    sc[t] = x;
    __syncthreads();
    for (int o = 1; o < 512; o <<= 1) {
        const int y = (t >= o) ? sc[t - o] : 0;
        __syncthreads();
        x += y;
        sc[t] = x;
        __syncthreads();
    }
    if (t < nb) { bucket_base[t] = x - v; cursor[t] = x - v; }
    if (t == nb - 1) { bucket_base[nb] = x; row_ptr[N] = x; }
}

// K3: partition (dst,src) pairs into bucket-contiguous tmp with clustered writes
__global__ __launch_bounds__(256) void partition_kernel(const int* __restrict__ src, const int* __restrict__ dst,
                                                        int E, int nb, int* __restrict__ cursor,
                                                        unsigned long long* __restrict__ tmp) {
    __shared__ int hist[512];
    __shared__ int tbase[512];
    for (int i = threadIdx.x; i < nb; i += 256) hist[i] = 0;
    __syncthreads();
    const int base = blockIdx.x * 4096;
    const int end = min(base + 4096, E);
    int myd[16], mys[16], myr[16];
#pragma unroll
    for (int j = 0; j < 16; ++j) {
        const int i = base + threadIdx.x + j * 256;
        if (i < end) {
            const int d = dst[i];
            myd[j] = d;
            mys[j] = src[i];
            myr[j] = atomicAdd(&hist[d >> 8], 1);
        } else {
            myd[j] = -1;
        }
    }
    __syncthreads();
    for (int i = threadIdx.x; i < nb; i += 256) {
        const int hv = hist[i];
        tbase[i] = hv ? atomicAdd(&cursor[i], hv) : 0;
    }
    __syncthreads();
#pragma unroll
    for (int j = 0; j < 16; ++j) {
        if (myd[j] >= 0) {
            const int b = myd[j] >> 8;
            tmp[(size_t)tbase[b] + myr[j]] = ((unsigned long long)(unsigned)myd[j] << 32) | (unsigned)mys[j];
        }
    }
}

// K4: per-bucket counting sort in LDS -> coalesced csr write + row_ptr for the bucket's nodes
__global__ __launch_bounds__(256) void bucket_sort_kernel(const unsigned long long* __restrict__ tmp,
                                                          const int* __restrict__ bucket_base,
                                                          int* __restrict__ row_ptr, int* __restrict__ csr,
                                                          int N) {
    __shared__ int hist[256];
    __shared__ int sc[256];
    __shared__ int off[256];
    __shared__ int outb[SEG_CAP];
    const int b = blockIdx.x;
    const int node0 = b << 8;
    const int nn = min(256, N - node0);
    const int s0 = bucket_base[b], s1 = bucket_base[b + 1];
    const int cnt = s1 - s0;
    const int t = threadIdx.x;
    hist[t] = 0;
    __syncthreads();
    for (int i = s0 + t; i < s1; i += 256) {
        const int d = (int)(tmp[i] >> 32) - node0;
        atomicAdd(&hist[d], 1);
    }
    __syncthreads();
    const int v = hist[t];
    int x = v;
    sc[t] = x;
    __syncthreads();
    for (int o = 1; o < 256; o <<= 1) {
        const int y = (t >= o) ? sc[t - o] : 0;
        __syncthreads();
        x += y;
        sc[t] = x;
        __syncthreads();
    }
    off[t] = x - v;
    if (t < nn) row_ptr[node0 + t] = s0 + (x - v);
    hist[t] = 0;   // reuse as per-node cursors
    __syncthreads();
    if (cnt <= SEG_CAP) {
        for (int i = s0 + t; i < s1; i += 256) {
            const unsigned long long pr = tmp[i];
            const int d = (int)(pr >> 32) - node0;
            const int p = off[d] + atomicAdd(&hist[d], 1);
            outb[p] = (int)(unsigned)(pr & 0xffffffffu);
        }
        __syncthreads();
        for (int i = t; i < cnt; i += 256) csr[s0 + i] = outb[i];
    } else {  // overflow fallback (statistically unreachable)
        for (int i = s0 + t; i < s1; i += 256) {
            const unsigned long long pr = tmp[i];
            const int d = (int)(pr >> 32) - node0;
            const int p = off[d] + atomicAdd(&hist[d], 1);
            csr[s0 + p] = (int)(unsigned)(pr & 0xffffffffu);
        }
    }
}

// ---------- W transpose+convert: Wt[n][k] = bf16(W[w_off + k*128 + n]) ----------
__global__ __launch_bounds__(256) void transpose_w_kernel(const void* __restrict__ W, long w_off, int K,
                                                          unsigned short* __restrict__ Wt,
                                                          const int* __restrict__ flagp) {
    const int bf = flagp[0];
    const int i = blockIdx.x * 256 + threadIdx.x;
    if (i >= 128 * K) return;
    const int n = i / K, k = i - n * K;
    const long s = w_off + (long)k * 128 + n;
    Wt[i] = bf ? ((const unsigned short*)W)[s] : f2us(((const float*)W)[s]);
}

// ---------- MFMA GEMM: C[M,128] = act(A[M,K] @ B[K,128] + bias) ----------
template <int C_BF>
__global__ __launch_bounds__(256) void mfma_gemm_kernel(const void* __restrict__ Ap, int a_input,
                                                        const unsigned short* __restrict__ Bt,
                                                        const void* __restrict__ bias, long bias_off,
                                                        void* __restrict__ Cp,
                                                        int M, int K, int do_relu,
                                                        const int* __restrict__ flagp) {
    __shared__ unsigned short As[128 * 40];
    __shared__ unsigned short Bs[128 * 40];
    const int bf = flagp[0];
    const int a_bf = a_input ? bf : 2;  // 2 == fp32 workspace
    const int t = threadIdx.x;
    const int bm = blockIdx.x * 128;
    const int lane = t & 63, wave = t >> 6;
    const int r = lane & 15, quad = lane >> 4;
    const int srow = t >> 1, skh = (t & 1) * 16;

    floatx4 acc[2][8];
#pragma unroll
    for (int mt = 0; mt < 2; ++mt)
#pragma unroll
        for (int nt = 0; nt < 8; ++nt)
#pragma unroll
            for (int q = 0; q < 4; ++q) acc[mt][nt][q] = 0.f;

    for (int k0 = 0; k0 < K; k0 += 32) {
        {
            const int grow = bm + srow;
            uint4 u0 = make_uint4(0, 0, 0, 0), u1 = u0;
            if (grow < M) {
                const long aidx = (long)grow * K + k0 + skh;
                if (a_bf == 1) {
                    const unsigned short* ap = (const unsigned short*)Ap + aidx;
                    u0 = ((const uint4*)ap)[0];
                    u1 = ((const uint4*)ap)[1];
                } else {
                    const float* ap = (const float*)Ap + aidx;
                    float4 f0 = ((const float4*)ap)[0];
                    float4 f1 = ((const float4*)ap)[1];
                    float4 f2 = ((const float4*)ap)[2];
                    float4 f3 = ((const float4*)ap)[3];
                    u0 = make_uint4(pack2(f0.x, f0.y), pack2(f0.z, f0.w), pack2(f1.x, f1.y), pack2(f1.z, f1.w));
                    u1 = make_uint4(pack2(f2.x, f2.y), pack2(f2.z, f2.w), pack2(f3.x, f3.y), pack2(f3.z, f3.w));
                }
            }
            *(uint4*)&As[srow * 40 + skh]     = u0;
            *(uint4*)&As[srow * 40 + skh + 8] = u1;
        }
        {
            const unsigned short* bp = Bt + (long)srow * K + k0 + skh;
            uint4 v0 = ((const uint4*)bp)[0];
            uint4 v1 = ((const uint4*)bp)[1];
            *(uint4*)&Bs[srow * 40 + skh]     = v0;
            *(uint4*)&Bs[srow * 40 + skh + 8] = v1;
        }
        __syncthreads();

        short8 afr[2];
        afr[0] = *(const short8*)&As[(wave * 32 + r) * 40 + quad * 8];
        afr[1] = *(const short8*)&As[(wave * 32 + 16 + r) * 40 + quad * 8];
#pragma unroll
        for (int nt = 0; nt < 8; ++nt) {
            short8 bfr = *(const short8*)&Bs[(nt * 16 + r) * 40 + quad * 8];
            acc[0][nt] = __builtin_amdgcn_mfma_f32_16x16x32_bf16(afr[0], bfr, acc[0][nt], 0, 0, 0);
            acc[1][nt] = __builtin_amdgcn_mfma_f32_16x16x32_bf16(afr[1], bfr, acc[1][nt], 0, 0, 0);
        }
        __syncthreads();
    }

    float bb[8];
#pragma unroll
    for (int nt = 0; nt < 8; ++nt) bb[nt] = bias ? ldw(bias, bias_off + nt * 16 + r, bf) : 0.f;

#pragma unroll
    for (int mt = 0; mt < 2; ++mt) {
        const int gr0 = bm + wave * 32 + mt * 16 + quad * 4;
#pragma unroll
        for (int reg = 0; reg < 4; ++reg) {
            const int grow = gr0 + reg;
            if (grow < M) {
#pragma unroll
                for (int nt = 0; nt < 8; ++nt) {
                    float v = acc[mt][nt][reg] + bb[nt];
                    if (do_relu) v = fmaxf(v, 0.f);
                    const long ci = (long)grow * HID + nt * 16 + r;
                    if (C_BF) ((unsigned short*)Cp)[ci] = f2us(v);
                    else      ((float*)Cp)[ci] = v;
                }
            }
        }
    }
}

// ---------- per-node attention scalars ----------
__global__ __launch_bounds__(256) void attn_kernel(const unsigned short* __restrict__ hp,
                                                   const void* __restrict__ att_src,
                                                   const void* __restrict__ att_dst, long a_off,
                                                   float* __restrict__ asrc, float* __restrict__ adst,
                                                   int N, const int* __restrict__ flagp) {
    __shared__ float sA[128], sD[128];
    const int bf = flagp[0];
    const int t = threadIdx.x;
    if (t < 128) { sA[t] = ldw(att_src, a_off + t, bf); sD[t] = ldw(att_dst, a_off + t, bf); }
    __syncthreads();
    const int gid = blockIdx.x * 256 + t;
    if (gid >= N * 4) return;
    const int n = gid >> 2, hd = gid & 3;
    const unsigned short* p = hp + (size_t)n * HID + hd * 32;
    float s1 = 0.f, s2 = 0.f;
#pragma unroll
    for (int q = 0; q < 4; ++q) {
        uint4 v = ((const uint4*)p)[q];
        unsigned arr[4] = {v.x, v.y, v.z, v.w};
#pragma unroll
        for (int j = 0; j < 4; ++j) {
            const int k = q * 8 + j * 2;
            float lo = lo2f(arr[j]);
            float hi = hi2f(arr[j]);
            s1 += lo * sA[hd * 32 + k] + hi * sA[hd * 32 + k + 1];
            s2 += lo * sD[hd * 32 + k] + hi * sD[hd * 32 + k + 1];
        }
    }
    asrc[gid] = s1;
    adst[gid] = s2;
}

// ---------- GAT aggregate + bias + LN + ReLU + residual (one wave per dst node) ----------
// Softmax shifted by the SELF-edge score (shift-invariant, no max reduction needed;
// spread of e within a node is O(10) for this data, fp32 exp safe to +/-88).
// Edge loop: two 32-lane halves each process a different edge; each lane covers
// 4 channels via one dwordx2 load; halves folded with shfl_xor(32) at the end.
__global__ __launch_bounds__(256) void gat_kernel(float* __restrict__ h,
                                                  const unsigned short* __restrict__ hp,
                                                  const float* __restrict__ asrc,
                                                  const float* __restrict__ adst,
                                                  const int* __restrict__ row_ptr,
                                                  const int* __restrict__ csr,
                                                  const void* __restrict__ bgat,
                                                  const void* __restrict__ lng,
                                                  const void* __restrict__ lnb, long w_off,
                                                  int N, const int* __restrict__ flagp) {
    __shared__ uint2 ebuf[4][320];
    const int bf = flagp[0];
    const int lane = threadIdx.x & 63;
    const int wslot = threadIdx.x >> 6;
    const int half = lane >> 5;
    const int ll = lane & 31;
    const int head4 = ll >> 3;     // head owning this lane's 4-channel group
    const int c0 = ll << 2;        // channel base 0..124
    const int n = (blockIdx.x << 2) | wslot;
    if (n >= N) return;

    const int e0 = row_ptr[n], e1 = row_ptr[n + 1];
    const float4 ad4 = *(const float4*)(adst + (size_t)n * 4);
    const float4 as4 = *(const float4*)(asrc + (size_t)n * 4);
    float4 es;
    es.x = lrelu(as4.x + ad4.x); es.y = lrelu(as4.y + ad4.y);
    es.z = lrelu(as4.z + ad4.z); es.w = lrelu(as4.w + ad4.w);

    // self contribution: exp(es - es) == 1; only half 0 accumulates it
    const uint2 us = *(const uint2*)(hp + (size_t)n * HID + c0);
    const float wself = half ? 0.f : 1.f;
    float4 acc;
    acc.x = wself * lo2f(us.x); acc.y = wself * hi2f(us.x);
    acc.z = wself * lo2f(us.y); acc.w = wself * hi2f(us.y);

    float4 dnp = make_float4(0.f, 0.f, 0.f, 0.f);  // per-lane denominator partials
    uint2* eb = ebuf[wslot];

    for (int base = e0; base < e1; base += 64) {
        const int cnt = min(64, e1 - base);
        int s = 0;
        float4 ex4 = make_float4(0.f, 0.f, 0.f, 0.f);
        if (lane < cnt) {
            s = csr[base + lane];
            const float4 a = *(const float4*)(asrc + (size_t)s * 4);
            ex4.x = __expf(lrelu(a.x + ad4.x) - es.x);
            ex4.y = __expf(lrelu(a.y + ad4.y) - es.y);
            ex4.z = __expf(lrelu(a.z + ad4.z) - es.z);
            ex4.w = __expf(lrelu(a.w + ad4.w) - es.w);
            dnp.x += ex4.x; dnp.y += ex4.y; dnp.z += ex4.z; dnp.w += ex4.w;
        }
        const unsigned su = (unsigned)s;
        eb[lane * 5 + 0] = make_uint2(su, __float_as_uint(ex4.x));
        eb[lane * 5 + 1] = make_uint2(su, __float_as_uint(ex4.y));
        eb[lane * 5 + 2] = make_uint2(su, __float_as_uint(ex4.z));
        eb[lane * 5 + 3] = make_uint2(su, __float_as_uint(ex4.w));
        // same-wave LDS RAW: compiler orders via lgkmcnt (writer/reader alias eb)

        float4 aA = make_float4(0.f, 0.f, 0.f, 0.f);
        float4 aB = make_float4(0.f, 0.f, 0.f, 0.f);
        int i = half;
#define GAT_EDGE(idx, A)                                                      \
        {                                                                     \
            const uint2 q = eb[(idx) * 5 + head4];                            \
            const uint2 u = *(const uint2*)(hp + (size_t)q.x * HID + c0);     \
            const float wq = __uint_as_float(q.y);                            \
            A.x = fmaf(wq, lo2f(u.x), A.x);                                   \
            A.y = fmaf(wq, hi2f(u.x), A.y);                                   \
            A.z = fmaf(wq, lo2f(u.y), A.z);                                   \
            A.w = fmaf(wq, hi2f(u.y), A.w);                                   \
        }
        for (; i + 2 < cnt; i += 4) {
            GAT_EDGE(i, aA);
            GAT_EDGE(i + 2, aB);
        }
        for (; i < cnt; i += 2) GAT_EDGE(i, aA);
#undef GAT_EDGE
        acc.x += aA.x + aB.x; acc.y += aA.y + aB.y;
        acc.z += aA.z + aB.z; acc.w += aA.w + aB.w;
    }

    // fold the two halves: every lane ends with the full 4-channel sums
    acc.x += __shfl_xor(acc.x, 32);
    acc.y += __shfl_xor(acc.y, 32);
    acc.z += __shfl_xor(acc.z, 32);
    acc.w += __shfl_xor(acc.w, 32);

    float4 dn;
    dn.x = wsum(dnp.x) + 1.f;
    dn.y = wsum(dnp.y) + 1.f;
    dn.z = wsum(dnp.z) + 1.f;
    dn.w = wsum(dnp.w) + 1.f;

    const float invd = 1.f / fmaxf(pick4(dn, head4), 1e-16f);
    acc.x *= invd; acc.y *= invd; acc.z *= invd; acc.w *= invd;
    acc.x += ldw(bgat, w_off + c0 + 0, bf);
    acc.y += ldw(bgat, w_off + c0 + 1, bf);
    acc.z += ldw(bgat, w_off + c0 + 2, bf);
    acc.w += ldw(bgat, w_off + c0 + 3, bf);

    // LN over 128 channels; channels duplicated across halves -> divide by 256
    const float mean = wsum(acc.x + acc.y + acc.z + acc.w) * (1.f / 256.f);
    const float d0 = acc.x - mean, d1 = acc.y - mean, d2 = acc.z - mean, d3 = acc.w - mean;
    const float var = wsum(d0 * d0 + d1 * d1 + d2 * d2 + d3 * d3) * (1.f / 256.f);
    const float rstd = rsqrtf(var + LN_EPS);
    float o0 = d0 * rstd * ldw(lng, w_off + c0 + 0, bf) + ldw(lnb, w_off + c0 + 0, bf);
    float o1 = d1 * rstd * ldw(lng, w_off + c0 + 1, bf) + ldw(lnb, w_off + c0 + 1, bf);
    float o2 = d2 * rstd * ldw(lng, w_off + c0 + 2, bf) + ldw(lnb, w_off + c0 + 2, bf);
    float o3 = d3 * rstd * ldw(lng, w_off + c0 + 3, bf) + ldw(lnb, w_off + c0 + 3, bf);
    o0 = fmaxf(o0, 0.f); o1 = fmaxf(o1, 0.f); o2 = fmaxf(o2, 0.f); o3 = fmaxf(o3, 0.f);

    if (half == 0) {
        const float4 r = *(const float4*)(h + (size_t)n * HID + c0);
        *(float4*)(h + (size_t)n * HID + c0) = make_float4(o0 + r.x, o1 + r.y, o2 + r.z, o3 + r.w);
    }
}

// ---------- pooling (sorted batch -> contiguous ranges, no atomics) ----------
__global__ __launch_bounds__(256) void pool_kernel(const float* __restrict__ h, const int* __restrict__ batch,
                                                   void* __restrict__ out, int N,
                                                   const int* __restrict__ flagp) {
    const int g = blockIdx.x;
    int a = 0, b = N;
    while (a < b) { int mid = (a + b) >> 1; if (batch[mid] < g) a = mid + 1; else b = mid; }
    const int lo = a;
    b = N;
    while (a < b) { int mid = (a + b) >> 1; if (batch[mid] <= g) a = mid + 1; else b = mid; }
    const int hi = a;

    const int col = threadIdx.x & 127;
    const int half = threadIdx.x >> 7;
    float s = 0.f;
    for (int r = lo + half; r < hi; r += 2) s += h[(size_t)r * HID + col];
    __shared__ float part[128];
    if (half == 0) part[col] = s;
    __syncthreads();
    if (half == 1) {
        const float tot = part[col] + s;
        const float v = tot / fmaxf((float)(hi - lo), 1.f);
        if (flagp[0]) ((unsigned short*)out)[g * HID + col] = f2us(v);
        else          ((float*)out)[g * HID + col] = v;
    }
}

// ---------- launch ----------
extern "C" void kernel_launch(void* const* d_in, const int* in_sizes, int n_in,
                              void* d_out, int out_size, void* d_ws, size_t ws_size,
                              hipStream_t stream) {
    const void* x     = d_in[0];
    const void* W_in  = d_in[1];
    const void* b_in  = d_in[2];
    const void* W_gat = d_in[3];
    const void* att_s = d_in[4];
    const void* att_d = d_in[5];
    const void* b_gat = d_in[6];
    const void* ln_g  = d_in[7];
    const void* ln_b  = d_in[8];
    const int* edge_index = (const int*)d_in[9];
    const int* batch      = (const int*)d_in[10];

    const int N = in_sizes[10];
    const int E = in_sizes[9] / 2;
    const int IN_DIM = in_sizes[0] / N;
    const int n_graphs = out_size / HID;

    const int* esrc = edge_index;
    const int* edst = edge_index + E;

    char* w = (char*)d_ws;
    auto carve = [&](size_t bytes) -> void* {
        void* p = (void*)w;
        w += (bytes + 255) & ~(size_t)255;
        return p;
    };
    int* flag             = (int*)carve(256);
    int* row_ptr          = (int*)carve((size_t)(N + 1) * 4);
    int* csr              = (int*)carve((size_t)E * 4);
    float* asrc           = (float*)carve((size_t)N * 4 * 4);
    float* adst           = (float*)carve((size_t)N * 4 * 4);
    int* bucket_cnt       = (int*)carve(512 * 4);
    int* bucket_base      = (int*)carve(513 * 4);
    int* cursor           = (int*)carve(512 * 4);
    unsigned short* Wt_in = (unsigned short*)carve((size_t)HID * IN_DIM * 2);
    unsigned short* Wt_g  = (unsigned short*)carve((size_t)HID * HID * 2);
    float* h              = (float*)carve((size_t)N * HID * 4);
    unsigned short* hp    = (unsigned short*)carve((size_t)N * HID * 2);
    // tmp (E x 8B) aliases h: only live during CSR build, before h is first written
    unsigned long long* tmp = (unsigned long long*)h;
    (void)ws_size; (void)n_in;

    detect_kernel<<<1, 64, 0, stream>>>((const float*)x, flag);

    // CSR build via bucket partition (256 dst-nodes per bucket)
    const int nb = (N + 255) >> 8;
    const int ntiles = (E + 4095) / 4096;
    zero_int_kernel<<<2, 256, 0, stream>>>(bucket_cnt, 512);
    bucket_hist_kernel<<<ntiles, 256, 0, stream>>>(edst, E, nb, bucket_cnt);
    bucket_scan_kernel<<<1, 512, 0, stream>>>(bucket_cnt, bucket_base, cursor, nb, row_ptr, N);
    partition_kernel<<<ntiles, 256, 0, stream>>>(esrc, edst, E, nb, cursor, tmp);
    bucket_sort_kernel<<<nb, 256, 0, stream>>>(tmp, bucket_base, row_ptr, csr, N);

    // input projection: h = relu(x @ W_in + b_in)
    transpose_w_kernel<<<(HID * IN_DIM + 255) / 256, 256, 0, stream>>>(W_in, 0, IN_DIM, Wt_in, flag);
    mfma_gemm_kernel<0><<<(N + 127) / 128, 256, 0, stream>>>(x, 1, Wt_in, b_in, 0, h, N, IN_DIM, 1, flag);

    for (int l = 0; l < 3; ++l) {
        transpose_w_kernel<<<(HID * HID + 255) / 256, 256, 0, stream>>>(W_gat, (long)l * HID * HID, HID, Wt_g, flag);
        mfma_gemm_kernel<1><<<(N + 127) / 128, 256, 0, stream>>>(h, 0, Wt_g, nullptr, 0, hp, N, HID, 0, flag);
        attn_kernel<<<(N * 4 + 255) / 256, 256, 0, stream>>>(hp, att_s, att_d, (long)l * HID,
                                                             asrc, adst, N, flag);
        gat_kernel<<<(N + 3) / 4, 256, 0, stream>>>(h, hp, asrc, adst, row_ptr, csr,
                                                    b_gat, ln_g, ln_b, (long)l * HID, N, flag);
    }

    pool_kernel<<<n_graphs, 256, 0, stream>>>(h, batch, d_out, N, flag);
}

// Round 3
// 809.846 us; speedup vs baseline: 1.1124x; 1.1124x over previous
//
#include <hip/hip_runtime.h>
#include <hip/hip_bf16.h>

#define HID 128
#define NEG_SLOPE 0.2f
#define LN_EPS 1e-5f
#define SEG_CAP 8192   // max edges per 256-node bucket (mean 4096, sigma~64)

typedef __attribute__((ext_vector_type(8))) short short8;
typedef __attribute__((ext_vector_type(4))) float floatx4;

// ---------- helpers ----------
__device__ __forceinline__ float us2f(unsigned short u) {
    union { unsigned int i; float f; } c; c.i = ((unsigned int)u) << 16; return c.f;
}
__device__ __forceinline__ float lo2f(unsigned u) {
    union { unsigned int i; float f; } c; c.i = u << 16; return c.f;
}
__device__ __forceinline__ float hi2f(unsigned u) {
    union { unsigned int i; float f; } c; c.i = u & 0xffff0000u; return c.f;
}
__device__ __forceinline__ unsigned short f2us(float f) {  // RNE bf16 pack
    union { float f; unsigned u; } c; c.f = f;
    unsigned r = c.u + 0x7FFF + ((c.u >> 16) & 1);
    return (unsigned short)(r >> 16);
}
__device__ __forceinline__ unsigned pack2(float a, float b) {
    return (unsigned)f2us(a) | ((unsigned)f2us(b) << 16);
}
__device__ __forceinline__ float ldw(const void* p, long i, int bf) {
    return bf ? us2f(((const unsigned short*)p)[i]) : ((const float*)p)[i];
}
__device__ __forceinline__ float lrelu(float x) { return x > 0.f ? x : NEG_SLOPE * x; }
__device__ __forceinline__ float wsum32(float x) {   // reduce within a 32-lane half
#pragma unroll
    for (int o = 16; o > 0; o >>= 1) x += __shfl_xor(x, o);
    return x;
}
__device__ __forceinline__ float pick4(float4 v, int h) {
    return h == 0 ? v.x : (h == 1 ? v.y : (h == 2 ? v.z : v.w));
}

// ---------- dtype sniff ----------
__global__ void detect_kernel(const float* __restrict__ x, int* __restrict__ flag) {
    float v = x[threadIdx.x];
    int bad = (!(v == v)) || (fabsf(v) > 1e6f);
    unsigned long long m = __ballot(bad);
    if (threadIdx.x == 0) flag[0] = (m != 0ull) ? 1 : 0;
}

__global__ __launch_bounds__(256) void zero_int_kernel(int* p, int n) {
    int i = blockIdx.x * 256 + threadIdx.x;
    if (i < n) p[i] = 0;
}

// ---------- CSR build: bucket partition (256 dst-nodes per bucket) ----------
// K1: per-tile LDS histogram -> global bucket counts (few global atomics)
__global__ __launch_bounds__(256) void bucket_hist_kernel(const int* __restrict__ dst, int E, int nb,
                                                          int* __restrict__ bucket_cnt) {
    __shared__ int hist[512];
    for (int i = threadIdx.x; i < nb; i += 256) hist[i] = 0;
    __syncthreads();
    const int base = blockIdx.x * 4096;
    const int end = min(base + 4096, E);
    for (int i = base + threadIdx.x; i < end; i += 256)
        atomicAdd(&hist[dst[i] >> 8], 1);
    __syncthreads();
    for (int i = threadIdx.x; i < nb; i += 256)
        if (hist[i]) atomicAdd(&bucket_cnt[i], hist[i]);
}

// K2: scan bucket counts -> bucket_base (csr segment starts), init cursors, row_ptr[N]
__global__ __launch_bounds__(512) void bucket_scan_kernel(const int* __restrict__ bucket_cnt,
                                                          int* __restrict__ bucket_base,
                                                          int* __restrict__ cursor,
                                                          int nb, int* __restrict__ row_ptr, int N) {
    __shared__ int sc[512];
    const int t = threadIdx.x;
    const int v = (t < nb) ? bucket_cnt[t] : 0;
    int x = v;
    sc[t] = x;
    __syncthreads();
    for (int o = 1; o < 512; o <<= 1) {
        const int y = (t >= o) ? sc[t - o] : 0;
        __syncthreads();
        x += y;
        sc[t] = x;
        __syncthreads();
    }
    if (t < nb) { bucket_base[t] = x - v; cursor[t] = x - v; }
    if (t == nb - 1) { bucket_base[nb] = x; row_ptr[N] = x; }
}

// K3: partition (dst,src) pairs into bucket-contiguous tmp with clustered writes
__global__ __launch_bounds__(256) void partition_kernel(const int* __restrict__ src, const int* __restrict__ dst,
                                                        int E, int nb, int* __restrict__ cursor,
                                                        unsigned long long* __restrict__ tmp) {
    __shared__ int hist[512];
    __shared__ int tbase[512];
    for (int i = threadIdx.x; i < nb; i += 256) hist[i] = 0;
    __syncthreads();
    const int base = blockIdx.x * 4096;
    const int end = min(base + 4096, E);
    int myd[16], mys[16], myr[16];
#pragma unroll
    for (int j = 0; j < 16; ++j) {
        const int i = base + threadIdx.x + j * 256;
        if (i < end) {
            const int d = dst[i];
            myd[j] = d;
            mys[j] = src[i];
            myr[j] = atomicAdd(&hist[d >> 8], 1);
        } else {
            myd[j] = -1;
        }
    }
    __syncthreads();
    for (int i = threadIdx.x; i < nb; i += 256) {
        const int hv = hist[i];
        tbase[i] = hv ? atomicAdd(&cursor[i], hv) : 0;
    }
    __syncthreads();
#pragma unroll
    for (int j = 0; j < 16; ++j) {
        if (myd[j] >= 0) {
            const int b = myd[j] >> 8;
            tmp[(size_t)tbase[b] + myr[j]] = ((unsigned long long)(unsigned)myd[j] << 32) | (unsigned)mys[j];
        }
    }
}

// K4: per-bucket counting sort in LDS -> coalesced csr write + row_ptr for the bucket's nodes
__global__ __launch_bounds__(256) void bucket_sort_kernel(const unsigned long long* __restrict__ tmp,
                                                          const int* __restrict__ bucket_base,
                                                          int* __restrict__ row_ptr, int* __restrict__ csr,
                                                          int N) {
    __shared__ int hist[256];
    __shared__ int sc[256];
    __shared__ int off[256];
    __shared__ int outb[SEG_CAP];
    const int b = blockIdx.x;
    const int node0 = b << 8;
    const int nn = min(256, N - node0);
    const int s0 = bucket_base[b], s1 = bucket_base[b + 1];
    const int cnt = s1 - s0;
    const int t = threadIdx.x;
    hist[t] = 0;
    __syncthreads();
    for (int i = s0 + t; i < s1; i += 256) {
        const int d = (int)(tmp[i] >> 32) - node0;
        atomicAdd(&hist[d], 1);
    }
    __syncthreads();
    const int v = hist[t];
    int x = v;
    sc[t] = x;
    __syncthreads();
    for (int o = 1; o < 256; o <<= 1) {
        const int y = (t >= o) ? sc[t - o] : 0;
        __syncthreads();
        x += y;
        sc[t] = x;
        __syncthreads();
    }
    off[t] = x - v;
    if (t < nn) row_ptr[node0 + t] = s0 + (x - v);
    hist[t] = 0;   // reuse as per-node cursors
    __syncthreads();
    if (cnt <= SEG_CAP) {
        for (int i = s0 + t; i < s1; i += 256) {
            const unsigned long long pr = tmp[i];
            const int d = (int)(pr >> 32) - node0;
            const int p = off[d] + atomicAdd(&hist[d], 1);
            outb[p] = (int)(unsigned)(pr & 0xffffffffu);
        }
        __syncthreads();
        for (int i = t; i < cnt; i += 256) csr[s0 + i] = outb[i];
    } else {  // overflow fallback (statistically unreachable)
        for (int i = s0 + t; i < s1; i += 256) {
            const unsigned long long pr = tmp[i];
            const int d = (int)(pr >> 32) - node0;
            const int p = off[d] + atomicAdd(&hist[d], 1);
            csr[s0 + p] = (int)(unsigned)(pr & 0xffffffffu);
        }
    }
}

// ---------- W transpose+convert: Wt[n][k] = bf16(W[w_off + k*128 + n]) ----------
__global__ __launch_bounds__(256) void transpose_w_kernel(const void* __restrict__ W, long w_off, int K,
                                                          unsigned short* __restrict__ Wt,
                                                          const int* __restrict__ flagp) {
    const int bf = flagp[0];
    const int i = blockIdx.x * 256 + threadIdx.x;
    if (i >= 128 * K) return;
    const int n = i / K, k = i - n * K;
    const long s = w_off + (long)k * 128 + n;
    Wt[i] = bf ? ((const unsigned short*)W)[s] : f2us(((const float*)W)[s]);
}

// ---------- MFMA GEMM: C[M,128] = act(A[M,K] @ B[K,128] + bias) ----------
template <int C_BF>
__global__ __launch_bounds__(256) void mfma_gemm_kernel(const void* __restrict__ Ap, int a_input,
                                                        const unsigned short* __restrict__ Bt,
                                                        const void* __restrict__ bias, long bias_off,
                                                        void* __restrict__ Cp,
                                                        int M, int K, int do_relu,
                                                        const int* __restrict__ flagp) {
    __shared__ unsigned short As[128 * 40];
    __shared__ unsigned short Bs[128 * 40];
    const int bf = flagp[0];
    const int a_bf = a_input ? bf : 2;  // 2 == fp32 workspace
    const int t = threadIdx.x;
    const int bm = blockIdx.x * 128;
    const int lane = t & 63, wave = t >> 6;
    const int r = lane & 15, quad = lane >> 4;
    const int srow = t >> 1, skh = (t & 1) * 16;

    floatx4 acc[2][8];
#pragma unroll
    for (int mt = 0; mt < 2; ++mt)
#pragma unroll
        for (int nt = 0; nt < 8; ++nt)
#pragma unroll
            for (int q = 0; q < 4; ++q) acc[mt][nt][q] = 0.f;

    for (int k0 = 0; k0 < K; k0 += 32) {
        {
            const int grow = bm + srow;
            uint4 u0 = make_uint4(0, 0, 0, 0), u1 = u0;
            if (grow < M) {
                const long aidx = (long)grow * K + k0 + skh;
                if (a_bf == 1) {
                    const unsigned short* ap = (const unsigned short*)Ap + aidx;
                    u0 = ((const uint4*)ap)[0];
                    u1 = ((const uint4*)ap)[1];
                } else {
                    const float* ap = (const float*)Ap + aidx;
                    float4 f0 = ((const float4*)ap)[0];
                    float4 f1 = ((const float4*)ap)[1];
                    float4 f2 = ((const float4*)ap)[2];
                    float4 f3 = ((const float4*)ap)[3];
                    u0 = make_uint4(pack2(f0.x, f0.y), pack2(f0.z, f0.w), pack2(f1.x, f1.y), pack2(f1.z, f1.w));
                    u1 = make_uint4(pack2(f2.x, f2.y), pack2(f2.z, f2.w), pack2(f3.x, f3.y), pack2(f3.z, f3.w));
                }
            }
            *(uint4*)&As[srow * 40 + skh]     = u0;
            *(uint4*)&As[srow * 40 + skh + 8] = u1;
        }
        {
            const unsigned short* bp = Bt + (long)srow * K + k0 + skh;
            uint4 v0 = ((const uint4*)bp)[0];
            uint4 v1 = ((const uint4*)bp)[1];
            *(uint4*)&Bs[srow * 40 + skh]     = v0;
            *(uint4*)&Bs[srow * 40 + skh + 8] = v1;
        }
        __syncthreads();

        short8 afr[2];
        afr[0] = *(const short8*)&As[(wave * 32 + r) * 40 + quad * 8];
        afr[1] = *(const short8*)&As[(wave * 32 + 16 + r) * 40 + quad * 8];
#pragma unroll
        for (int nt = 0; nt < 8; ++nt) {
            short8 bfr = *(const short8*)&Bs[(nt * 16 + r) * 40 + quad * 8];
            acc[0][nt] = __builtin_amdgcn_mfma_f32_16x16x32_bf16(afr[0], bfr, acc[0][nt], 0, 0, 0);
            acc[1][nt] = __builtin_amdgcn_mfma_f32_16x16x32_bf16(afr[1], bfr, acc[1][nt], 0, 0, 0);
        }
        __syncthreads();
    }

    float bb[8];
#pragma unroll
    for (int nt = 0; nt < 8; ++nt) bb[nt] = bias ? ldw(bias, bias_off + nt * 16 + r, bf) : 0.f;

#pragma unroll
    for (int mt = 0; mt < 2; ++mt) {
        const int gr0 = bm + wave * 32 + mt * 16 + quad * 4;
#pragma unroll
        for (int reg = 0; reg < 4; ++reg) {
            const int grow = gr0 + reg;
            if (grow < M) {
#pragma unroll
                for (int nt = 0; nt < 8; ++nt) {
                    float v = acc[mt][nt][reg] + bb[nt];
                    if (do_relu) v = fmaxf(v, 0.f);
                    const long ci = (long)grow * HID + nt * 16 + r;
                    if (C_BF) ((unsigned short*)Cp)[ci] = f2us(v);
                    else      ((float*)Cp)[ci] = v;
                }
            }
        }
    }
}

// ---------- per-node attention scalars ----------
__global__ __launch_bounds__(256) void attn_kernel(const unsigned short* __restrict__ hp,
                                                   const void* __restrict__ att_src,
                                                   const void* __restrict__ att_dst, long a_off,
                                                   float* __restrict__ asrc, float* __restrict__ adst,
                                                   int N, const int* __restrict__ flagp) {
    __shared__ float sA[128], sD[128];
    const int bf = flagp[0];
    const int t = threadIdx.x;
    if (t < 128) { sA[t] = ldw(att_src, a_off + t, bf); sD[t] = ldw(att_dst, a_off + t, bf); }
    __syncthreads();
    const int gid = blockIdx.x * 256 + t;
    if (gid >= N * 4) return;
    const int n = gid >> 2, hd = gid & 3;
    const unsigned short* p = hp + (size_t)n * HID + hd * 32;
    float s1 = 0.f, s2 = 0.f;
#pragma unroll
    for (int q = 0; q < 4; ++q) {
        uint4 v = ((const uint4*)p)[q];
        unsigned arr[4] = {v.x, v.y, v.z, v.w};
#pragma unroll
        for (int j = 0; j < 4; ++j) {
            const int k = q * 8 + j * 2;
            float lo = lo2f(arr[j]);
            float hi = hi2f(arr[j]);
            s1 += lo * sA[hd * 32 + k] + hi * sA[hd * 32 + k + 1];
            s2 += lo * sD[hd * 32 + k] + hi * sD[hd * 32 + k + 1];
        }
    }
    asrc[gid] = s1;
    adst[gid] = s2;
}

// ---------- GAT aggregate + bias + LN + ReLU + residual ----------
// ONE NODE PER 32-LANE HALF (2 independent nodes per wave, 8 per block).
// A half's 32 lanes cover all 128 channels (4/lane) -> per-node fixed work
// (self row, params, reductions, LN, residual) costs half a wave, and the
// edge loop runs 4 independent gather chains per half (8 outstanding loads
// per wave) to hide scattered-gather latency.
// Softmax is shifted by the SELF-edge score (shift-invariant; self weight == 1).
__global__ __launch_bounds__(256) void gat_kernel(float* __restrict__ h,
                                                  const unsigned short* __restrict__ hp,
                                                  const float* __restrict__ asrc,
                                                  const float* __restrict__ adst,
                                                  const int* __restrict__ row_ptr,
                                                  const int* __restrict__ csr,
                                                  const void* __restrict__ bgat,
                                                  const void* __restrict__ lng,
                                                  const void* __restrict__ lnb, long w_off,
                                                  int N, const int* __restrict__ flagp) {
    __shared__ uint2 ebuf[8][160];
    const int bf = flagp[0];
    const int lane = threadIdx.x & 63;
    const int wslot = threadIdx.x >> 6;
    const int half = lane >> 5;
    const int ll = lane & 31;
    const int head4 = ll >> 3;     // head owning this lane's 4-channel group
    const int c0 = ll << 2;        // channel base 0..124
    const int n = (blockIdx.x << 3) | (wslot << 1) | half;
    if (n >= N) return;

    const int e0 = row_ptr[n], e1 = row_ptr[n + 1];
    const float4 ad4 = *(const float4*)(adst + (size_t)n * 4);
    const float4 as4 = *(const float4*)(asrc + (size_t)n * 4);
    float4 es;
    es.x = lrelu(as4.x + ad4.x); es.y = lrelu(as4.y + ad4.y);
    es.z = lrelu(as4.z + ad4.z); es.w = lrelu(as4.w + ad4.w);

    // self contribution: exp(es - es) == 1
    const uint2 us = *(const uint2*)(hp + (size_t)n * HID + c0);
    float4 acc;
    acc.x = lo2f(us.x); acc.y = hi2f(us.x);
    acc.z = lo2f(us.y); acc.w = hi2f(us.y);

    float4 dnp = make_float4(0.f, 0.f, 0.f, 0.f);  // per-lane denominator partials
    uint2* eb = ebuf[(wslot << 1) | half];

    for (int base = e0; base < e1; base += 32) {
        const int cnt = min(32, e1 - base);
        int s = 0;
        float4 ex4 = make_float4(0.f, 0.f, 0.f, 0.f);
        if (ll < cnt) {
            s = csr[base + ll];
            const float4 a = *(const float4*)(asrc + (size_t)s * 4);
            ex4.x = __expf(lrelu(a.x + ad4.x) - es.x);
            ex4.y = __expf(lrelu(a.y + ad4.y) - es.y);
            ex4.z = __expf(lrelu(a.z + ad4.z) - es.z);
            ex4.w = __expf(lrelu(a.w + ad4.w) - es.w);
            dnp.x += ex4.x; dnp.y += ex4.y; dnp.z += ex4.z; dnp.w += ex4.w;
        }
        const unsigned su = (unsigned)s;
        eb[ll * 5 + 0] = make_uint2(su, __float_as_uint(ex4.x));
        eb[ll * 5 + 1] = make_uint2(su, __float_as_uint(ex4.y));
        eb[ll * 5 + 2] = make_uint2(su, __float_as_uint(ex4.z));
        eb[ll * 5 + 3] = make_uint2(su, __float_as_uint(ex4.w));
        // same-wave LDS RAW: compiler orders via lgkmcnt (writer/reader alias eb)

        float4 aA = make_float4(0.f, 0.f, 0.f, 0.f);
        float4 aB = make_float4(0.f, 0.f, 0.f, 0.f);
        float4 aC = make_float4(0.f, 0.f, 0.f, 0.f);
        float4 aD = make_float4(0.f, 0.f, 0.f, 0.f);
        int i = 0;
#define GAT_EDGE(idx, A)                                                      \
        {                                                                     \
            const uint2 q = eb[(idx) * 5 + head4];                            \
            const uint2 u = *(const uint2*)(hp + (size_t)q.x * HID + c0);     \
            const float wq = __uint_as_float(q.y);                            \
            A.x = fmaf(wq, lo2f(u.x), A.x);                                   \
            A.y = fmaf(wq, hi2f(u.x), A.y);                                   \
            A.z = fmaf(wq, lo2f(u.y), A.z);                                   \
            A.w = fmaf(wq, hi2f(u.y), A.w);                                   \
        }
        for (; i + 4 <= cnt; i += 4) {
            GAT_EDGE(i + 0, aA);
            GAT_EDGE(i + 1, aB);
            GAT_EDGE(i + 2, aC);
            GAT_EDGE(i + 3, aD);
        }
        for (; i < cnt; ++i) GAT_EDGE(i, aA);
#undef GAT_EDGE
        acc.x += (aA.x + aB.x) + (aC.x + aD.x);
        acc.y += (aA.y + aB.y) + (aC.y + aD.y);
        acc.z += (aA.z + aB.z) + (aC.z + aD.z);
        acc.w += (aA.w + aB.w) + (aC.w + aD.w);
    }

    float4 dn;
    dn.x = wsum32(dnp.x) + 1.f;
    dn.y = wsum32(dnp.y) + 1.f;
    dn.z = wsum32(dnp.z) + 1.f;
    dn.w = wsum32(dnp.w) + 1.f;

    const float invd = 1.f / fmaxf(pick4(dn, head4), 1e-16f);
    acc.x *= invd; acc.y *= invd; acc.z *= invd; acc.w *= invd;
    acc.x += ldw(bgat, w_off + c0 + 0, bf);
    acc.y += ldw(bgat, w_off + c0 + 1, bf);
    acc.z += ldw(bgat, w_off + c0 + 2, bf);
    acc.w += ldw(bgat, w_off + c0 + 3, bf);

    // LN over the node's 128 channels (4 per lane across the 32-lane half)
    const float mean = wsum32(acc.x + acc.y + acc.z + acc.w) * (1.f / 128.f);
    const float d0 = acc.x - mean, d1 = acc.y - mean, d2 = acc.z - mean, d3 = acc.w - mean;
    const float var = wsum32(d0 * d0 + d1 * d1 + d2 * d2 + d3 * d3) * (1.f / 128.f);
    const float rstd = rsqrtf(var + LN_EPS);
    float o0 = d0 * rstd * ldw(lng, w_off + c0 + 0, bf) + ldw(lnb, w_off + c0 + 0, bf);
    float o1 = d1 * rstd * ldw(lng, w_off + c0 + 1, bf) + ldw(lnb, w_off + c0 + 1, bf);
    float o2 = d2 * rstd * ldw(lng, w_off + c0 + 2, bf) + ldw(lnb, w_off + c0 + 2, bf);
    float o3 = d3 * rstd * ldw(lng, w_off + c0 + 3, bf) + ldw(lnb, w_off + c0 + 3, bf);
    o0 = fmaxf(o0, 0.f); o1 = fmaxf(o1, 0.f); o2 = fmaxf(o2, 0.f); o3 = fmaxf(o3, 0.f);

    const float4 r = *(const float4*)(h + (size_t)n * HID + c0);
    *(float4*)(h + (size_t)n * HID + c0) = make_float4(o0 + r.x, o1 + r.y, o2 + r.z, o3 + r.w);
}

// ---------- pooling (sorted batch -> contiguous ranges, no atomics) ----------
__global__ __launch_bounds__(256) void pool_kernel(const float* __restrict__ h, const int* __restrict__ batch,
                                                   void* __restrict__ out, int N,
                                                   const int* __restrict__ flagp) {
    const int g = blockIdx.x;
    int a = 0, b = N;
    while (a < b) { int mid = (a + b) >> 1; if (batch[mid] < g) a = mid + 1; else b = mid; }
    const int lo = a;
    b = N;
    while (a < b) { int mid = (a + b) >> 1; if (batch[mid] <= g) a = mid + 1; else b = mid; }
    const int hi = a;

    const int col = threadIdx.x & 127;
    const int half = threadIdx.x >> 7;
    float s = 0.f;
    for (int r = lo + half; r < hi; r += 2) s += h[(size_t)r * HID + col];
    __shared__ float part[128];
    if (half == 0) part[col] = s;
    __syncthreads();
    if (half == 1) {
        const float tot = part[col] + s;
        const float v = tot / fmaxf((float)(hi - lo), 1.f);
        if (flagp[0]) ((unsigned short*)out)[g * HID + col] = f2us(v);
        else          ((float*)out)[g * HID + col] = v;
    }
}

// ---------- launch ----------
extern "C" void kernel_launch(void* const* d_in, const int* in_sizes, int n_in,
                              void* d_out, int out_size, void* d_ws, size_t ws_size,
                              hipStream_t stream) {
    const void* x     = d_in[0];
    const void* W_in  = d_in[1];
    const void* b_in  = d_in[2];
    const void* W_gat = d_in[3];
    const void* att_s = d_in[4];
    const void* att_d = d_in[5];
    const void* b_gat = d_in[6];
    const void* ln_g  = d_in[7];
    const void* ln_b  = d_in[8];
    const int* edge_index = (const int*)d_in[9];
    const int* batch      = (const int*)d_in[10];

    const int N = in_sizes[10];
    const int E = in_sizes[9] / 2;
    const int IN_DIM = in_sizes[0] / N;
    const int n_graphs = out_size / HID;

    const int* esrc = edge_index;
    const int* edst = edge_index + E;

    char* w = (char*)d_ws;
    auto carve = [&](size_t bytes) -> void* {
        void* p = (void*)w;
        w += (bytes + 255) & ~(size_t)255;
        return p;
    };
    int* flag             = (int*)carve(256);
    int* row_ptr          = (int*)carve((size_t)(N + 1) * 4);
    int* csr              = (int*)carve((size_t)E * 4);
    float* asrc           = (float*)carve((size_t)N * 4 * 4);
    float* adst           = (float*)carve((size_t)N * 4 * 4);
    int* bucket_cnt       = (int*)carve(512 * 4);
    int* bucket_base      = (int*)carve(513 * 4);
    int* cursor           = (int*)carve(512 * 4);
    unsigned short* Wt_in = (unsigned short*)carve((size_t)HID * IN_DIM * 2);
    unsigned short* Wt_g  = (unsigned short*)carve((size_t)HID * HID * 2);
    float* h              = (float*)carve((size_t)N * HID * 4);
    unsigned short* hp    = (unsigned short*)carve((size_t)N * HID * 2);
    // tmp (E x 8B) aliases h: only live during CSR build, before h is first written
    unsigned long long* tmp = (unsigned long long*)h;
    (void)ws_size; (void)n_in;

    detect_kernel<<<1, 64, 0, stream>>>((const float*)x, flag);

    // CSR build via bucket partition (256 dst-nodes per bucket)
    const int nb = (N + 255) >> 8;
    const int ntiles = (E + 4095) / 4096;
    zero_int_kernel<<<2, 256, 0, stream>>>(bucket_cnt, 512);
    bucket_hist_kernel<<<ntiles, 256, 0, stream>>>(edst, E, nb, bucket_cnt);
    bucket_scan_kernel<<<1, 512, 0, stream>>>(bucket_cnt, bucket_base, cursor, nb, row_ptr, N);
    partition_kernel<<<ntiles, 256, 0, stream>>>(esrc, edst, E, nb, cursor, tmp);
    bucket_sort_kernel<<<nb, 256, 0, stream>>>(tmp, bucket_base, row_ptr, csr, N);

    // input projection: h = relu(x @ W_in + b_in)
    transpose_w_kernel<<<(HID * IN_DIM + 255) / 256, 256, 0, stream>>>(W_in, 0, IN_DIM, Wt_in, flag);
    mfma_gemm_kernel<0><<<(N + 127) / 128, 256, 0, stream>>>(x, 1, Wt_in, b_in, 0, h, N, IN_DIM, 1, flag);

    for (int l = 0; l < 3; ++l) {
        transpose_w_kernel<<<(HID * HID + 255) / 256, 256, 0, stream>>>(W_gat, (long)l * HID * HID, HID, Wt_g, flag);
        mfma_gemm_kernel<1><<<(N + 127) / 128, 256, 0, stream>>>(h, 0, Wt_g, nullptr, 0, hp, N, HID, 0, flag);
        attn_kernel<<<(N * 4 + 255) / 256, 256, 0, stream>>>(hp, att_s, att_d, (long)l * HID,
                                                             asrc, adst, N, flag);
        gat_kernel<<<(N + 7) / 8, 256, 0, stream>>>(h, hp, asrc, adst, row_ptr, csr,
                                                    b_gat, ln_g, ln_b, (long)l * HID, N, flag);
    }

    pool_kernel<<<n_graphs, 256, 0, stream>>>(h, batch, d_out, N, flag);
}

// Round 4
// 770.680 us; speedup vs baseline: 1.1689x; 1.0508x over previous
//
#include <hip/hip_runtime.h>
#include <hip/hip_bf16.h>

#define HID 128
#define NEG_SLOPE 0.2f
#define LN_EPS 1e-5f
#define SEG_CAP 8192   // max edges per 256-node bucket (mean 4096, sigma~64)

typedef __attribute__((ext_vector_type(8))) short short8;
typedef __attribute__((ext_vector_type(4))) float floatx4;

// ---------- helpers ----------
__device__ __forceinline__ float us2f(unsigned short u) {
    union { unsigned int i; float f; } c; c.i = ((unsigned int)u) << 16; return c.f;
}
__device__ __forceinline__ float lo2f(unsigned u) {
    union { unsigned int i; float f; } c; c.i = u << 16; return c.f;
}
__device__ __forceinline__ float hi2f(unsigned u) {
    union { unsigned int i; float f; } c; c.i = u & 0xffff0000u; return c.f;
}
__device__ __forceinline__ unsigned short f2us(float f) {  // RNE bf16 pack
    union { float f; unsigned u; } c; c.f = f;
    unsigned r = c.u + 0x7FFF + ((c.u >> 16) & 1);
    return (unsigned short)(r >> 16);
}
__device__ __forceinline__ unsigned pack2(float a, float b) {
    return (unsigned)f2us(a) | ((unsigned)f2us(b) << 16);
}
__device__ __forceinline__ float ldw(const void* p, long i, int bf) {
    return bf ? us2f(((const unsigned short*)p)[i]) : ((const float*)p)[i];
}
__device__ __forceinline__ float lrelu(float x) { return x > 0.f ? x : NEG_SLOPE * x; }
__device__ __forceinline__ float wsum32(float x) {   // reduce within a 32-lane half
#pragma unroll
    for (int o = 16; o > 0; o >>= 1) x += __shfl_xor(x, o);
    return x;
}
__device__ __forceinline__ float pick4(float4 v, int h) {
    return h == 0 ? v.x : (h == 1 ? v.y : (h == 2 ? v.z : v.w));
}

// ---------- init: dtype sniff + zero bucket counters (one dispatch) ----------
__global__ __launch_bounds__(256) void init_kernel(const float* __restrict__ x, int* __restrict__ flag,
                                                   int* __restrict__ bucket_cnt) {
    const int t = blockIdx.x * 256 + threadIdx.x;
    if (t < 512) bucket_cnt[t] = 0;
    if (blockIdx.x == 0 && threadIdx.x < 64) {
        float v = x[threadIdx.x];
        int bad = (!(v == v)) || (fabsf(v) > 1e6f);
        unsigned long long m = __ballot(bad);
        if (threadIdx.x == 0) flag[0] = (m != 0ull) ? 1 : 0;
    }
}

// ---------- CSR build: bucket partition (256 dst-nodes per bucket) ----------
// K1: per-tile LDS histogram -> global bucket counts (few global atomics)
__global__ __launch_bounds__(256) void bucket_hist_kernel(const int* __restrict__ dst, int E, int nb,
                                                          int* __restrict__ bucket_cnt) {
    __shared__ int hist[512];
    for (int i = threadIdx.x; i < nb; i += 256) hist[i] = 0;
    __syncthreads();
    const int base = blockIdx.x * 4096;
    const int end = min(base + 4096, E);
    for (int i = base + threadIdx.x; i < end; i += 256)
        atomicAdd(&hist[dst[i] >> 8], 1);
    __syncthreads();
    for (int i = threadIdx.x; i < nb; i += 256)
        if (hist[i]) atomicAdd(&bucket_cnt[i], hist[i]);
}

// K2: scan bucket counts -> bucket_base (csr segment starts), init cursors, row_ptr[N]
__global__ __launch_bounds__(512) void bucket_scan_kernel(const int* __restrict__ bucket_cnt,
                                                          int* __restrict__ bucket_base,
                                                          int* __restrict__ cursor,
                                                          int nb, int* __restrict__ row_ptr, int N) {
    __shared__ int sc[512];
    const int t = threadIdx.x;
    const int v = (t < nb) ? bucket_cnt[t] : 0;
    int x = v;
    sc[t] = x;
    __syncthreads();
    for (int o = 1; o < 512; o <<= 1) {
        const int y = (t >= o) ? sc[t - o] : 0;
        __syncthreads();
        x += y;
        sc[t] = x;
        __syncthreads();
    }
    if (t < nb) { bucket_base[t] = x - v; cursor[t] = x - v; }
    if (t == nb - 1) { bucket_base[nb] = x; row_ptr[N] = x; }
}

// K3: partition (dst,src) pairs into bucket-contiguous tmp with clustered writes
__global__ __launch_bounds__(256) void partition_kernel(const int* __restrict__ src, const int* __restrict__ dst,
                                                        int E, int nb, int* __restrict__ cursor,
                                                        unsigned long long* __restrict__ tmp) {
    __shared__ int hist[512];
    __shared__ int tbase[512];
    for (int i = threadIdx.x; i < nb; i += 256) hist[i] = 0;
    __syncthreads();
    const int base = blockIdx.x * 4096;
    const int end = min(base + 4096, E);
    int myd[16], mys[16], myr[16];
#pragma unroll
    for (int j = 0; j < 16; ++j) {
        const int i = base + threadIdx.x + j * 256;
        if (i < end) {
            const int d = dst[i];
            myd[j] = d;
            mys[j] = src[i];
            myr[j] = atomicAdd(&hist[d >> 8], 1);
        } else {
            myd[j] = -1;
        }
    }
    __syncthreads();
    for (int i = threadIdx.x; i < nb; i += 256) {
        const int hv = hist[i];
        tbase[i] = hv ? atomicAdd(&cursor[i], hv) : 0;
    }
    __syncthreads();
#pragma unroll
    for (int j = 0; j < 16; ++j) {
        if (myd[j] >= 0) {
            const int b = myd[j] >> 8;
            tmp[(size_t)tbase[b] + myr[j]] = ((unsigned long long)(unsigned)myd[j] << 32) | (unsigned)mys[j];
        }
    }
}

// K4: per-bucket counting sort in LDS -> coalesced csr write + row_ptr for the bucket's nodes
__global__ __launch_bounds__(256) void bucket_sort_kernel(const unsigned long long* __restrict__ tmp,
                                                          const int* __restrict__ bucket_base,
                                                          int* __restrict__ row_ptr, int* __restrict__ csr,
                                                          int N) {
    __shared__ int hist[256];
    __shared__ int sc[256];
    __shared__ int off[256];
    __shared__ int outb[SEG_CAP];
    const int b = blockIdx.x;
    const int node0 = b << 8;
    const int nn = min(256, N - node0);
    const int s0 = bucket_base[b], s1 = bucket_base[b + 1];
    const int cnt = s1 - s0;
    const int t = threadIdx.x;
    hist[t] = 0;
    __syncthreads();
    for (int i = s0 + t; i < s1; i += 256) {
        const int d = (int)(tmp[i] >> 32) - node0;
        atomicAdd(&hist[d], 1);
    }
    __syncthreads();
    const int v = hist[t];
    int x = v;
    sc[t] = x;
    __syncthreads();
    for (int o = 1; o < 256; o <<= 1) {
        const int y = (t >= o) ? sc[t - o] : 0;
        __syncthreads();
        x += y;
        sc[t] = x;
        __syncthreads();
    }
    off[t] = x - v;
    if (t < nn) row_ptr[node0 + t] = s0 + (x - v);
    hist[t] = 0;   // reuse as per-node cursors
    __syncthreads();
    if (cnt <= SEG_CAP) {
        for (int i = s0 + t; i < s1; i += 256) {
            const unsigned long long pr = tmp[i];
            const int d = (int)(pr >> 32) - node0;
            const int p = off[d] + atomicAdd(&hist[d], 1);
            outb[p] = (int)(unsigned)(pr & 0xffffffffu);
        }
        __syncthreads();
        for (int i = t; i < cnt; i += 256) csr[s0 + i] = outb[i];
    } else {  // overflow fallback (statistically unreachable)
        for (int i = s0 + t; i < s1; i += 256) {
            const unsigned long long pr = tmp[i];
            const int d = (int)(pr >> 32) - node0;
            const int p = off[d] + atomicAdd(&hist[d], 1);
            csr[s0 + p] = (int)(unsigned)(pr & 0xffffffffu);
        }
    }
}

// ---------- W transpose+convert: Wt[n][k] = bf16(W[w_off + k*128 + n]) ----------
__global__ __launch_bounds__(256) void transpose_w_kernel(const void* __restrict__ W, long w_off, int K,
                                                          unsigned short* __restrict__ Wt,
                                                          const int* __restrict__ flagp) {
    const int bf = flagp[0];
    const int i = blockIdx.x * 256 + threadIdx.x;
    if (i >= 128 * K) return;
    const int n = i / K, k = i - n * K;
    const long s = w_off + (long)k * 128 + n;
    Wt[i] = bf ? ((const unsigned short*)W)[s] : f2us(((const float*)W)[s]);
}

// all 3 GAT layer weights in one dispatch: Wt[l][n][k] = bf16(W[l][k][n]), K=N=128
__global__ __launch_bounds__(256) void transpose_wg_kernel(const void* __restrict__ W,
                                                           unsigned short* __restrict__ Wt,
                                                           const int* __restrict__ flagp) {
    const int bf = flagp[0];
    const int i = blockIdx.x * 256 + threadIdx.x;
    if (i >= 3 * 128 * 128) return;
    const int l = i >> 14, j = i & 16383;
    const int n = j >> 7, k = j & 127;
    const long s = (long)l * 16384 + (long)k * 128 + n;
    Wt[i] = bf ? ((const unsigned short*)W)[s] : f2us(((const float*)W)[s]);
}

// ---------- MFMA GEMM: C[M,128] = act(A[M,K] @ B[K,128] + bias) ----------
// FUSE=1 (layer GEMMs): also computes per-node attention scalars
//   asrc[n,h] = sum_k hp_bf16[n, h*32+k]*attS[h*32+k]  (and adst with attD)
// directly from the accumulators (head h = cols {2h,2h+1}*16 + r; reduce over
// the quad's 16 r-lanes with shfl_xor butterflies).
template <int C_BF, int FUSE>
__global__ __launch_bounds__(256) void mfma_gemm_kernel(const void* __restrict__ Ap, int a_input,
                                                        const unsigned short* __restrict__ Bt,
                                                        const void* __restrict__ bias, long bias_off,
                                                        void* __restrict__ Cp,
                                                        const void* __restrict__ attS,
                                                        const void* __restrict__ attD, long a_off,
                                                        float* __restrict__ asrc, float* __restrict__ adst,
                                                        int M, int K, int do_relu,
                                                        const int* __restrict__ flagp) {
    __shared__ unsigned short As[128 * 40];
    __shared__ unsigned short Bs[128 * 40];
    const int bf = flagp[0];
    const int a_bf = a_input ? (bf ? 1 : 2) : 2;  // 1 == bf16, 2 == fp32
    const int t = threadIdx.x;
    const int bm = blockIdx.x * 128;
    const int lane = t & 63, wave = t >> 6;
    const int r = lane & 15, quad = lane >> 4;
    const int srow = t >> 1, skh = (t & 1) * 16;

    floatx4 acc[2][8];
#pragma unroll
    for (int mt = 0; mt < 2; ++mt)
#pragma unroll
        for (int nt = 0; nt < 8; ++nt)
#pragma unroll
            for (int q = 0; q < 4; ++q) acc[mt][nt][q] = 0.f;

    for (int k0 = 0; k0 < K; k0 += 32) {
        {
            const int grow = bm + srow;
            uint4 u0 = make_uint4(0, 0, 0, 0), u1 = u0;
            if (grow < M) {
                const long aidx = (long)grow * K + k0 + skh;
                if (a_bf == 1) {
                    const unsigned short* ap = (const unsigned short*)Ap + aidx;
                    u0 = ((const uint4*)ap)[0];
                    u1 = ((const uint4*)ap)[1];
                } else {
                    const float* ap = (const float*)Ap + aidx;
                    float4 f0 = ((const float4*)ap)[0];
                    float4 f1 = ((const float4*)ap)[1];
                    float4 f2 = ((const float4*)ap)[2];
                    float4 f3 = ((const float4*)ap)[3];
                    u0 = make_uint4(pack2(f0.x, f0.y), pack2(f0.z, f0.w), pack2(f1.x, f1.y), pack2(f1.z, f1.w));
                    u1 = make_uint4(pack2(f2.x, f2.y), pack2(f2.z, f2.w), pack2(f3.x, f3.y), pack2(f3.z, f3.w));
                }
            }
            *(uint4*)&As[srow * 40 + skh]     = u0;
            *(uint4*)&As[srow * 40 + skh + 8] = u1;
        }
        {
            const unsigned short* bp = Bt + (long)srow * K + k0 + skh;
            uint4 v0 = ((const uint4*)bp)[0];
            uint4 v1 = ((const uint4*)bp)[1];
            *(uint4*)&Bs[srow * 40 + skh]     = v0;
            *(uint4*)&Bs[srow * 40 + skh + 8] = v1;
        }
        __syncthreads();

        short8 afr[2];
        afr[0] = *(const short8*)&As[(wave * 32 + r) * 40 + quad * 8];
        afr[1] = *(const short8*)&As[(wave * 32 + 16 + r) * 40 + quad * 8];
#pragma unroll
        for (int nt = 0; nt < 8; ++nt) {
            short8 bfr = *(const short8*)&Bs[(nt * 16 + r) * 40 + quad * 8];
            acc[0][nt] = __builtin_amdgcn_mfma_f32_16x16x32_bf16(afr[0], bfr, acc[0][nt], 0, 0, 0);
            acc[1][nt] = __builtin_amdgcn_mfma_f32_16x16x32_bf16(afr[1], bfr, acc[1][nt], 0, 0, 0);
        }
        __syncthreads();
    }

    if (FUSE) {
        // layer epilogue: bf16 store + fused attention scalars (no bias, no relu)
        float aS[8], aD[8];
#pragma unroll
        for (int nt = 0; nt < 8; ++nt) {
            aS[nt] = ldw(attS, a_off + nt * 16 + r, bf);
            aD[nt] = ldw(attD, a_off + nt * 16 + r, bf);
        }
#pragma unroll
        for (int mt = 0; mt < 2; ++mt) {
#pragma unroll
            for (int reg = 0; reg < 4; ++reg) {
                const int grow = bm + wave * 32 + mt * 16 + quad * 4 + reg;
                if (grow < M) {   // uniform within the quad -> shfl partners stay active
                    float s0 = 0.f, s1 = 0.f, s2 = 0.f, s3 = 0.f;
                    float d0 = 0.f, d1 = 0.f, d2 = 0.f, d3 = 0.f;
#pragma unroll
                    for (int nt = 0; nt < 8; ++nt) {
                        const float v = acc[mt][nt][reg];
                        const unsigned short us = f2us(v);
                        ((unsigned short*)Cp)[(long)grow * HID + nt * 16 + r] = us;
                        const float vr = us2f(us);
                        if (nt < 2)      { s0 = fmaf(vr, aS[nt], s0); d0 = fmaf(vr, aD[nt], d0); }
                        else if (nt < 4) { s1 = fmaf(vr, aS[nt], s1); d1 = fmaf(vr, aD[nt], d1); }
                        else if (nt < 6) { s2 = fmaf(vr, aS[nt], s2); d2 = fmaf(vr, aD[nt], d2); }
                        else             { s3 = fmaf(vr, aS[nt], s3); d3 = fmaf(vr, aD[nt], d3); }
                    }
#pragma unroll
                    for (int o = 1; o < 16; o <<= 1) {
                        s0 += __shfl_xor(s0, o); s1 += __shfl_xor(s1, o);
                        s2 += __shfl_xor(s2, o); s3 += __shfl_xor(s3, o);
                        d0 += __shfl_xor(d0, o); d1 += __shfl_xor(d1, o);
                        d2 += __shfl_xor(d2, o); d3 += __shfl_xor(d3, o);
                    }
                    const int hsel = r & 3;
                    const float sv = hsel == 0 ? s0 : (hsel == 1 ? s1 : (hsel == 2 ? s2 : s3));
                    const float dv = hsel == 0 ? d0 : (hsel == 1 ? d1 : (hsel == 2 ? d2 : d3));
                    if (r < 4)      asrc[(size_t)grow * 4 + hsel] = sv;
                    else if (r < 8) adst[(size_t)grow * 4 + hsel] = dv;
                }
            }
        }
    } else {
        float bb[8];
#pragma unroll
        for (int nt = 0; nt < 8; ++nt) bb[nt] = bias ? ldw(bias, bias_off + nt * 16 + r, bf) : 0.f;

#pragma unroll
        for (int mt = 0; mt < 2; ++mt) {
            const int gr0 = bm + wave * 32 + mt * 16 + quad * 4;
#pragma unroll
            for (int reg = 0; reg < 4; ++reg) {
                const int grow = gr0 + reg;
                if (grow < M) {
#pragma unroll
                    for (int nt = 0; nt < 8; ++nt) {
                        float v = acc[mt][nt][reg] + bb[nt];
                        if (do_relu) v = fmaxf(v, 0.f);
                        const long ci = (long)grow * HID + nt * 16 + r;
                        if (C_BF) ((unsigned short*)Cp)[ci] = f2us(v);
                        else      ((float*)Cp)[ci] = v;
                    }
                }
            }
        }
    }
}

// ---------- GAT aggregate + bias + LN + ReLU + residual ----------
// ONE NODE PER 32-LANE HALF (2 independent nodes per wave, 8 per block).
// Softmax shifted by the SELF-edge score (shift-invariant; self weight == 1).
__global__ __launch_bounds__(256) void gat_kernel(float* __restrict__ h,
                                                  const unsigned short* __restrict__ hp,
                                                  const float* __restrict__ asrc,
                                                  const float* __restrict__ adst,
                                                  const int* __restrict__ row_ptr,
                                                  const int* __restrict__ csr,
                                                  const void* __restrict__ bgat,
                                                  const void* __restrict__ lng,
                                                  const void* __restrict__ lnb, long w_off,
                                                  int N, const int* __restrict__ flagp) {
    __shared__ uint2 ebuf[8][160];
    const int bf = flagp[0];
    const int lane = threadIdx.x & 63;
    const int wslot = threadIdx.x >> 6;
    const int half = lane >> 5;
    const int ll = lane & 31;
    const int head4 = ll >> 3;     // head owning this lane's 4-channel group
    const int c0 = ll << 2;        // channel base 0..124
    const int n = (blockIdx.x << 3) | (wslot << 1) | half;
    if (n >= N) return;

    const int e0 = row_ptr[n], e1 = row_ptr[n + 1];
    const float4 ad4 = *(const float4*)(adst + (size_t)n * 4);
    const float4 as4 = *(const float4*)(asrc + (size_t)n * 4);
    float4 es;
    es.x = lrelu(as4.x + ad4.x); es.y = lrelu(as4.y + ad4.y);
    es.z = lrelu(as4.z + ad4.z); es.w = lrelu(as4.w + ad4.w);

    // self contribution: exp(es - es) == 1
    const uint2 us = *(const uint2*)(hp + (size_t)n * HID + c0);
    float4 acc;
    acc.x = lo2f(us.x); acc.y = hi2f(us.x);
    acc.z = lo2f(us.y); acc.w = hi2f(us.y);

    float4 dnp = make_float4(0.f, 0.f, 0.f, 0.f);  // per-lane denominator partials
    uint2* eb = ebuf[(wslot << 1) | half];

    for (int base = e0; base < e1; base += 32) {
        const int cnt = min(32, e1 - base);
        int s = 0;
        float4 ex4 = make_float4(0.f, 0.f, 0.f, 0.f);
        if (ll < cnt) {
            s = csr[base + ll];
            const float4 a = *(const float4*)(asrc + (size_t)s * 4);
            ex4.x = __expf(lrelu(a.x + ad4.x) - es.x);
            ex4.y = __expf(lrelu(a.y + ad4.y) - es.y);
            ex4.z = __expf(lrelu(a.z + ad4.z) - es.z);
            ex4.w = __expf(lrelu(a.w + ad4.w) - es.w);
            dnp.x += ex4.x; dnp.y += ex4.y; dnp.z += ex4.z; dnp.w += ex4.w;
        }
        const unsigned su = (unsigned)s;
        eb[ll * 5 + 0] = make_uint2(su, __float_as_uint(ex4.x));
        eb[ll * 5 + 1] = make_uint2(su, __float_as_uint(ex4.y));
        eb[ll * 5 + 2] = make_uint2(su, __float_as_uint(ex4.z));
        eb[ll * 5 + 3] = make_uint2(su, __float_as_uint(ex4.w));
        // same-wave LDS RAW: compiler orders via lgkmcnt (writer/reader alias eb)

        float4 aA = make_float4(0.f, 0.f, 0.f, 0.f);
        float4 aB = make_float4(0.f, 0.f, 0.f, 0.f);
        float4 aC = make_float4(0.f, 0.f, 0.f, 0.f);
        float4 aD = make_float4(0.f, 0.f, 0.f, 0.f);
        int i = 0;
#define GAT_EDGE(idx, A)                                                      \
        {                                                                     \
            const uint2 q = eb[(idx) * 5 + head4];                            \
            const uint2 u = *(const uint2*)(hp + (size_t)q.x * HID + c0);     \
            const float wq = __uint_as_float(q.y);                            \
            A.x = fmaf(wq, lo2f(u.x), A.x);                                   \
            A.y = fmaf(wq, hi2f(u.x), A.y);                                   \
            A.z = fmaf(wq, lo2f(u.y), A.z);                                   \
            A.w = fmaf(wq, hi2f(u.y), A.w);                                   \
        }
        for (; i + 4 <= cnt; i += 4) {
            GAT_EDGE(i + 0, aA);
            GAT_EDGE(i + 1, aB);
            GAT_EDGE(i + 2, aC);
            GAT_EDGE(i + 3, aD);
        }
        for (; i < cnt; ++i) GAT_EDGE(i, aA);
#undef GAT_EDGE
        acc.x += (aA.x + aB.x) + (aC.x + aD.x);
        acc.y += (aA.y + aB.y) + (aC.y + aD.y);
        acc.z += (aA.z + aB.z) + (aC.z + aD.z);
        acc.w += (aA.w + aB.w) + (aC.w + aD.w);
    }

    float4 dn;
    dn.x = wsum32(dnp.x) + 1.f;
    dn.y = wsum32(dnp.y) + 1.f;
    dn.z = wsum32(dnp.z) + 1.f;
    dn.w = wsum32(dnp.w) + 1.f;

    const float invd = 1.f / fmaxf(pick4(dn, head4), 1e-16f);
    acc.x *= invd; acc.y *= invd; acc.z *= invd; acc.w *= invd;
    acc.x += ldw(bgat, w_off + c0 + 0, bf);
    acc.y += ldw(bgat, w_off + c0 + 1, bf);
    acc.z += ldw(bgat, w_off + c0 + 2, bf);
    acc.w += ldw(bgat, w_off + c0 + 3, bf);

    // LN over the node's 128 channels (4 per lane across the 32-lane half)
    const float mean = wsum32(acc.x + acc.y + acc.z + acc.w) * (1.f / 128.f);
    const float d0 = acc.x - mean, d1 = acc.y - mean, d2 = acc.z - mean, d3 = acc.w - mean;
    const float var = wsum32(d0 * d0 + d1 * d1 + d2 * d2 + d3 * d3) * (1.f / 128.f);
    const float rstd = rsqrtf(var + LN_EPS);
    float o0 = d0 * rstd * ldw(lng, w_off + c0 + 0, bf) + ldw(lnb, w_off + c0 + 0, bf);
    float o1 = d1 * rstd * ldw(lng, w_off + c0 + 1, bf) + ldw(lnb, w_off + c0 + 1, bf);
    float o2 = d2 * rstd * ldw(lng, w_off + c0 + 2, bf) + ldw(lnb, w_off + c0 + 2, bf);
    float o3 = d3 * rstd * ldw(lng, w_off + c0 + 3, bf) + ldw(lnb, w_off + c0 + 3, bf);
    o0 = fmaxf(o0, 0.f); o1 = fmaxf(o1, 0.f); o2 = fmaxf(o2, 0.f); o3 = fmaxf(o3, 0.f);

    const float4 r = *(const float4*)(h + (size_t)n * HID + c0);
    *(float4*)(h + (size_t)n * HID + c0) = make_float4(o0 + r.x, o1 + r.y, o2 + r.z, o3 + r.w);
}

// ---------- pooling (sorted batch -> contiguous ranges, no atomics) ----------
// 1024 threads (16 waves): 8 row-slices per graph for MLP on the 1-block/CU grid
__global__ __launch_bounds__(1024) void pool_kernel(const float* __restrict__ h, const int* __restrict__ batch,
                                                    void* __restrict__ out, int N,
                                                    const int* __restrict__ flagp) {
    const int g = blockIdx.x;
    int a = 0, b = N;
    while (a < b) { int mid = (a + b) >> 1; if (batch[mid] < g) a = mid + 1; else b = mid; }
    const int lo = a;
    b = N;
    while (a < b) { int mid = (a + b) >> 1; if (batch[mid] <= g) a = mid + 1; else b = mid; }
    const int hi = a;

    const int col = threadIdx.x & 127;
    const int slot = threadIdx.x >> 7;   // 0..7
    float s = 0.f;
    for (int r = lo + slot; r < hi; r += 8) s += h[(size_t)r * HID + col];
    __shared__ float part[8][128];
    part[slot][col] = s;
    __syncthreads();
    if (threadIdx.x < 128) {
        float tot = part[0][threadIdx.x];
#pragma unroll
        for (int p = 1; p < 8; ++p) tot += part[p][threadIdx.x];
        const float v = tot / fmaxf((float)(hi - lo), 1.f);
        if (flagp[0]) ((unsigned short*)out)[g * HID + threadIdx.x] = f2us(v);
        else          ((float*)out)[g * HID + threadIdx.x] = v;
    }
}

// ---------- launch ----------
extern "C" void kernel_launch(void* const* d_in, const int* in_sizes, int n_in,
                              void* d_out, int out_size, void* d_ws, size_t ws_size,
                              hipStream_t stream) {
    const void* x     = d_in[0];
    const void* W_in  = d_in[1];
    const void* b_in  = d_in[2];
    const void* W_gat = d_in[3];
    const void* att_s = d_in[4];
    const void* att_d = d_in[5];
    const void* b_gat = d_in[6];
    const void* ln_g  = d_in[7];
    const void* ln_b  = d_in[8];
    const int* edge_index = (const int*)d_in[9];
    const int* batch      = (const int*)d_in[10];

    const int N = in_sizes[10];
    const int E = in_sizes[9] / 2;
    const int IN_DIM = in_sizes[0] / N;
    const int n_graphs = out_size / HID;

    const int* esrc = edge_index;
    const int* edst = edge_index + E;

    char* w = (char*)d_ws;
    auto carve = [&](size_t bytes) -> void* {
        void* p = (void*)w;
        w += (bytes + 255) & ~(size_t)255;
        return p;
    };
    int* flag             = (int*)carve(256);
    int* row_ptr          = (int*)carve((size_t)(N + 1) * 4);
    int* csr              = (int*)carve((size_t)E * 4);
    float* asrc           = (float*)carve((size_t)N * 4 * 4);
    float* adst           = (float*)carve((size_t)N * 4 * 4);
    int* bucket_cnt       = (int*)carve(512 * 4);
    int* bucket_base      = (int*)carve(513 * 4);
    int* cursor           = (int*)carve(512 * 4);
    unsigned short* Wt_in = (unsigned short*)carve((size_t)HID * IN_DIM * 2);
    unsigned short* Wt_g  = (unsigned short*)carve((size_t)3 * HID * HID * 2);
    float* h              = (float*)carve((size_t)N * HID * 4);
    unsigned short* hp    = (unsigned short*)carve((size_t)N * HID * 2);
    // tmp (E x 8B) aliases h: only live during CSR build, before h is first written
    unsigned long long* tmp = (unsigned long long*)h;
    (void)ws_size; (void)n_in;

    // init: dtype sniff + zero bucket counters
    init_kernel<<<2, 256, 0, stream>>>((const float*)x, flag, bucket_cnt);

    // CSR build via bucket partition (256 dst-nodes per bucket)
    const int nb = (N + 255) >> 8;
    const int ntiles = (E + 4095) / 4096;
    bucket_hist_kernel<<<ntiles, 256, 0, stream>>>(edst, E, nb, bucket_cnt);
    bucket_scan_kernel<<<1, 512, 0, stream>>>(bucket_cnt, bucket_base, cursor, nb, row_ptr, N);
    partition_kernel<<<ntiles, 256, 0, stream>>>(esrc, edst, E, nb, cursor, tmp);
    bucket_sort_kernel<<<nb, 256, 0, stream>>>(tmp, bucket_base, row_ptr, csr, N);

    // weight prep (hoisted; all 3 GAT layers in one dispatch)
    transpose_w_kernel<<<(HID * IN_DIM + 255) / 256, 256, 0, stream>>>(W_in, 0, IN_DIM, Wt_in, flag);
    transpose_wg_kernel<<<(3 * HID * HID + 255) / 256, 256, 0, stream>>>(W_gat, Wt_g, flag);

    // input projection: h = relu(x @ W_in + b_in)
    mfma_gemm_kernel<0, 0><<<(N + 127) / 128, 256, 0, stream>>>(
        x, 1, Wt_in, b_in, 0, h, nullptr, nullptr, 0, nullptr, nullptr, N, IN_DIM, 1, flag);

    for (int l = 0; l < 3; ++l) {
        mfma_gemm_kernel<1, 1><<<(N + 127) / 128, 256, 0, stream>>>(
            h, 0, Wt_g + (size_t)l * HID * HID, nullptr, 0, hp,
            att_s, att_d, (long)l * HID, asrc, adst, N, HID, 0, flag);
        gat_kernel<<<(N + 7) / 8, 256, 0, stream>>>(h, hp, asrc, adst, row_ptr, csr,
                                                    b_gat, ln_g, ln_b, (long)l * HID, N, flag);
    }

    pool_kernel<<<n_graphs, 1024, 0, stream>>>(h, batch, d_out, N, flag);
}

// Round 5
// 750.813 us; speedup vs baseline: 1.1999x; 1.0265x over previous
//
#include <hip/hip_runtime.h>
#include <hip/hip_bf16.h>

#define HID 128
#define NEG_SLOPE 0.2f
#define LN_EPS 1e-5f
#define SEG_CAP 8192   // max edges per 256-node bucket (mean 4096, sigma~64)

typedef __attribute__((ext_vector_type(8))) short short8;
typedef __attribute__((ext_vector_type(4))) float floatx4;

// ---------- helpers ----------
__device__ __forceinline__ float us2f(unsigned short u) {
    union { unsigned int i; float f; } c; c.i = ((unsigned int)u) << 16; return c.f;
}
__device__ __forceinline__ float lo2f(unsigned u) {
    union { unsigned int i; float f; } c; c.i = u << 16; return c.f;
}
__device__ __forceinline__ float hi2f(unsigned u) {
    union { unsigned int i; float f; } c; c.i = u & 0xffff0000u; return c.f;
}
__device__ __forceinline__ unsigned short f2us(float f) {  // RNE bf16 pack
    union { float f; unsigned u; } c; c.f = f;
    unsigned r = c.u + 0x7FFF + ((c.u >> 16) & 1);
    return (unsigned short)(r >> 16);
}
__device__ __forceinline__ unsigned pack2(float a, float b) {
    return (unsigned)f2us(a) | ((unsigned)f2us(b) << 16);
}
__device__ __forceinline__ float ldw(const void* p, long i, int bf) {
    return bf ? us2f(((const unsigned short*)p)[i]) : ((const float*)p)[i];
}
__device__ __forceinline__ float lrelu(float x) { return x > 0.f ? x : NEG_SLOPE * x; }
__device__ __forceinline__ float wsum32(float x) {   // reduce within a 32-lane half
#pragma unroll
    for (int o = 16; o > 0; o >>= 1) x += __shfl_xor(x, o);
    return x;
}
__device__ __forceinline__ float pick4(float4 v, int h) {
    return h == 0 ? v.x : (h == 1 ? v.y : (h == 2 ? v.z : v.w));
}

// ---------- init: dtype sniff + zero bucket counters (one dispatch) ----------
__global__ __launch_bounds__(256) void init_kernel(const float* __restrict__ x, int* __restrict__ flag,
                                                   int* __restrict__ bucket_cnt) {
    const int t = blockIdx.x * 256 + threadIdx.x;
    if (t < 512) bucket_cnt[t] = 0;
    if (blockIdx.x == 0 && threadIdx.x < 64) {
        float v = x[threadIdx.x];
        int bad = (!(v == v)) || (fabsf(v) > 1e6f);
        unsigned long long m = __ballot(bad);
        if (threadIdx.x == 0) flag[0] = (m != 0ull) ? 1 : 0;
    }
}

// ---------- CSR build: bucket partition (256 dst-nodes per bucket) ----------
// K1: per-tile LDS histogram -> global bucket counts (few global atomics)
__global__ __launch_bounds__(256) void bucket_hist_kernel(const int* __restrict__ dst, int E, int nb,
                                                          int* __restrict__ bucket_cnt) {
    __shared__ int hist[512];
    for (int i = threadIdx.x; i < nb; i += 256) hist[i] = 0;
    __syncthreads();
    const int base = blockIdx.x * 4096;
    const int end = min(base + 4096, E);
    for (int i = base + threadIdx.x; i < end; i += 256)
        atomicAdd(&hist[dst[i] >> 8], 1);
    __syncthreads();
    for (int i = threadIdx.x; i < nb; i += 256)
        if (hist[i]) atomicAdd(&bucket_cnt[i], hist[i]);
}

// K2: scan bucket counts -> bucket_base (csr segment starts), init cursors, row_ptr[N]
__global__ __launch_bounds__(512) void bucket_scan_kernel(const int* __restrict__ bucket_cnt,
                                                          int* __restrict__ bucket_base,
                                                          int* __restrict__ cursor,
                                                          int nb, int* __restrict__ row_ptr, int N) {
    __shared__ int sc[512];
    const int t = threadIdx.x;
    const int v = (t < nb) ? bucket_cnt[t] : 0;
    int x = v;
    sc[t] = x;
    __syncthreads();
    for (int o = 1; o < 512; o <<= 1) {
        const int y = (t >= o) ? sc[t - o] : 0;
        __syncthreads();
        x += y;
        sc[t] = x;
        __syncthreads();
    }
    if (t < nb) { bucket_base[t] = x - v; cursor[t] = x - v; }
    if (t == nb - 1) { bucket_base[nb] = x; row_ptr[N] = x; }
}

// K3: partition (dst,src) pairs into bucket-contiguous tmp with clustered writes
__global__ __launch_bounds__(256) void partition_kernel(const int* __restrict__ src, const int* __restrict__ dst,
                                                        int E, int nb, int* __restrict__ cursor,
                                                        unsigned long long* __restrict__ tmp) {
    __shared__ int hist[512];
    __shared__ int tbase[512];
    for (int i = threadIdx.x; i < nb; i += 256) hist[i] = 0;
    __syncthreads();
    const int base = blockIdx.x * 4096;
    const int end = min(base + 4096, E);
    int myd[16], mys[16], myr[16];
#pragma unroll
    for (int j = 0; j < 16; ++j) {
        const int i = base + threadIdx.x + j * 256;
        if (i < end) {
            const int d = dst[i];
            myd[j] = d;
            mys[j] = src[i];
            myr[j] = atomicAdd(&hist[d >> 8], 1);
        } else {
            myd[j] = -1;
        }
    }
    __syncthreads();
    for (int i = threadIdx.x; i < nb; i += 256) {
        const int hv = hist[i];
        tbase[i] = hv ? atomicAdd(&cursor[i], hv) : 0;
    }
    __syncthreads();
#pragma unroll
    for (int j = 0; j < 16; ++j) {
        if (myd[j] >= 0) {
            const int b = myd[j] >> 8;
            tmp[(size_t)tbase[b] + myr[j]] = ((unsigned long long)(unsigned)myd[j] << 32) | (unsigned)mys[j];
        }
    }
}

// K4: per-bucket counting sort in LDS -> coalesced csr write + row_ptr for the bucket's nodes
__global__ __launch_bounds__(256) void bucket_sort_kernel(const unsigned long long* __restrict__ tmp,
                                                          const int* __restrict__ bucket_base,
                                                          int* __restrict__ row_ptr, int* __restrict__ csr,
                                                          int N) {
    __shared__ int hist[256];
    __shared__ int sc[256];
    __shared__ int off[256];
    __shared__ int outb[SEG_CAP];
    const int b = blockIdx.x;
    const int node0 = b << 8;
    const int nn = min(256, N - node0);
    const int s0 = bucket_base[b], s1 = bucket_base[b + 1];
    const int cnt = s1 - s0;
    const int t = threadIdx.x;
    hist[t] = 0;
    __syncthreads();
    for (int i = s0 + t; i < s1; i += 256) {
        const int d = (int)(tmp[i] >> 32) - node0;
        atomicAdd(&hist[d], 1);
    }
    __syncthreads();
    const int v = hist[t];
    int x = v;
    sc[t] = x;
    __syncthreads();
    for (int o = 1; o < 256; o <<= 1) {
        const int y = (t >= o) ? sc[t - o] : 0;
        __syncthreads();
        x += y;
        sc[t] = x;
        __syncthreads();
    }
    off[t] = x - v;
    if (t < nn) row_ptr[node0 + t] = s0 + (x - v);
    hist[t] = 0;   // reuse as per-node cursors
    __syncthreads();
    if (cnt <= SEG_CAP) {
        for (int i = s0 + t; i < s1; i += 256) {
            const unsigned long long pr = tmp[i];
            const int d = (int)(pr >> 32) - node0;
            const int p = off[d] + atomicAdd(&hist[d], 1);
            outb[p] = (int)(unsigned)(pr & 0xffffffffu);
        }
        __syncthreads();
        for (int i = t; i < cnt; i += 256) csr[s0 + i] = outb[i];
    } else {  // overflow fallback (statistically unreachable)
        for (int i = s0 + t; i < s1; i += 256) {
            const unsigned long long pr = tmp[i];
            const int d = (int)(pr >> 32) - node0;
            const int p = off[d] + atomicAdd(&hist[d], 1);
            csr[s0 + p] = (int)(unsigned)(pr & 0xffffffffu);
        }
    }
}

// ---------- W transpose+convert: Wt[n][k] = bf16(W[w_off + k*128 + n]) ----------
__global__ __launch_bounds__(256) void transpose_w_kernel(const void* __restrict__ W, long w_off, int K,
                                                          unsigned short* __restrict__ Wt,
                                                          const int* __restrict__ flagp) {
    const int bf = flagp[0];
    const int i = blockIdx.x * 256 + threadIdx.x;
    if (i >= 128 * K) return;
    const int n = i / K, k = i - n * K;
    const long s = w_off + (long)k * 128 + n;
    Wt[i] = bf ? ((const unsigned short*)W)[s] : f2us(((const float*)W)[s]);
}

// all 3 GAT layer weights in one dispatch: Wt[l][n][k] = bf16(W[l][k][n]), K=N=128
__global__ __launch_bounds__(256) void transpose_wg_kernel(const void* __restrict__ W,
                                                           unsigned short* __restrict__ Wt,
                                                           const int* __restrict__ flagp) {
    const int bf = flagp[0];
    const int i = blockIdx.x * 256 + threadIdx.x;
    if (i >= 3 * 128 * 128) return;
    const int l = i >> 14, j = i & 16383;
    const int n = j >> 7, k = j & 127;
    const long s = (long)l * 16384 + (long)k * 128 + n;
    Wt[i] = bf ? ((const unsigned short*)W)[s] : f2us(((const float*)W)[s]);
}

// ---------- MFMA GEMM: C[M,128] = act(A[M,K] @ B[K,128] + bias) ----------
// Software-pipelined: register prefetch of chunk k+1 issued BEFORE the MFMA
// block of chunk k; double-buffered LDS; ONE barrier per k-step (step i's
// reads of buf[cur] precede its barrier; step i+1's stores to buf[cur] follow
// it). HBM latency hides under MFMA + frag reads.
// FUSE=1 (layer GEMMs): also computes per-node attention scalars
//   asrc[n,h] = sum_k hp_bf16[n, h*32+k]*attS[h*32+k]  (and adst with attD)
// from the accumulators (reduce over the quad's 16 r-lanes with shfl_xor).
template <int C_BF, int FUSE>
__global__ __launch_bounds__(256) void mfma_gemm_kernel(const void* __restrict__ Ap, int a_input,
                                                        const unsigned short* __restrict__ Bt,
                                                        const void* __restrict__ bias, long bias_off,
                                                        void* __restrict__ Cp,
                                                        const void* __restrict__ attS,
                                                        const void* __restrict__ attD, long a_off,
                                                        float* __restrict__ asrc, float* __restrict__ adst,
                                                        int M, int K, int do_relu,
                                                        const int* __restrict__ flagp) {
    __shared__ unsigned short As[2][128 * 40];
    __shared__ unsigned short Bs[2][128 * 40];
    const int bf = flagp[0];
    const int a_bf = a_input ? (bf ? 1 : 2) : 2;  // 1 == bf16, 2 == fp32
    const int t = threadIdx.x;
    const int bm = blockIdx.x * 128;
    const int lane = t & 63, wave = t >> 6;
    const int r = lane & 15, quad = lane >> 4;
    const int srow = t >> 1, skh = (t & 1) * 16;
    const int grow = bm + srow;

    floatx4 acc[2][8];
#pragma unroll
    for (int mt = 0; mt < 2; ++mt)
#pragma unroll
        for (int nt = 0; nt < 8; ++nt)
#pragma unroll
            for (int q = 0; q < 4; ++q) acc[mt][nt][q] = 0.f;

    auto loadAB = [&](int k0, uint4& u0, uint4& u1, uint4& v0, uint4& v1) {
        u0 = make_uint4(0, 0, 0, 0); u1 = u0;
        if (grow < M) {
            const long aidx = (long)grow * K + k0 + skh;
            if (a_bf == 1) {
                const unsigned short* ap = (const unsigned short*)Ap + aidx;
                u0 = ((const uint4*)ap)[0];
                u1 = ((const uint4*)ap)[1];
            } else {
                const float* ap = (const float*)Ap + aidx;
                float4 f0 = ((const float4*)ap)[0];
                float4 f1 = ((const float4*)ap)[1];
                float4 f2 = ((const float4*)ap)[2];
                float4 f3 = ((const float4*)ap)[3];
                u0 = make_uint4(pack2(f0.x, f0.y), pack2(f0.z, f0.w), pack2(f1.x, f1.y), pack2(f1.z, f1.w));
                u1 = make_uint4(pack2(f2.x, f2.y), pack2(f2.z, f2.w), pack2(f3.x, f3.y), pack2(f3.z, f3.w));
            }
        }
        const unsigned short* bp = Bt + (long)srow * K + k0 + skh;
        v0 = ((const uint4*)bp)[0];
        v1 = ((const uint4*)bp)[1];
    };

    // prologue: stage chunk 0
    uint4 a0, a1, b0, b1;
    loadAB(0, a0, a1, b0, b1);
    *(uint4*)&As[0][srow * 40 + skh]     = a0;
    *(uint4*)&As[0][srow * 40 + skh + 8] = a1;
    *(uint4*)&Bs[0][srow * 40 + skh]     = b0;
    *(uint4*)&Bs[0][srow * 40 + skh + 8] = b1;
    __syncthreads();

    int cur = 0;
    for (int k0 = 0; k0 < K; k0 += 32) {
        const bool have = (k0 + 32) < K;
        if (have) loadAB(k0 + 32, a0, a1, b0, b1);   // issue before MFMA: latency hidden

        short8 afr[2];
        afr[0] = *(const short8*)&As[cur][(wave * 32 + r) * 40 + quad * 8];
        afr[1] = *(const short8*)&As[cur][(wave * 32 + 16 + r) * 40 + quad * 8];
#pragma unroll
        for (int nt = 0; nt < 8; ++nt) {
            short8 bfr = *(const short8*)&Bs[cur][(nt * 16 + r) * 40 + quad * 8];
            acc[0][nt] = __builtin_amdgcn_mfma_f32_16x16x32_bf16(afr[0], bfr, acc[0][nt], 0, 0, 0);
            acc[1][nt] = __builtin_amdgcn_mfma_f32_16x16x32_bf16(afr[1], bfr, acc[1][nt], 0, 0, 0);
        }

        if (have) {
            cur ^= 1;
            *(uint4*)&As[cur][srow * 40 + skh]     = a0;
            *(uint4*)&As[cur][srow * 40 + skh + 8] = a1;
            *(uint4*)&Bs[cur][srow * 40 + skh]     = b0;
            *(uint4*)&Bs[cur][srow * 40 + skh + 8] = b1;
            __syncthreads();
        }
    }

    if (FUSE) {
        // layer epilogue: bf16 store + fused attention scalars (no bias, no relu)
        float aS[8], aD[8];
#pragma unroll
        for (int nt = 0; nt < 8; ++nt) {
            aS[nt] = ldw(attS, a_off + nt * 16 + r, bf);
            aD[nt] = ldw(attD, a_off + nt * 16 + r, bf);
        }
#pragma unroll
        for (int mt = 0; mt < 2; ++mt) {
#pragma unroll
            for (int reg = 0; reg < 4; ++reg) {
                const int gr = bm + wave * 32 + mt * 16 + quad * 4 + reg;
                if (gr < M) {   // uniform within the quad -> shfl partners stay active
                    float s0 = 0.f, s1 = 0.f, s2 = 0.f, s3 = 0.f;
                    float d0 = 0.f, d1 = 0.f, d2 = 0.f, d3 = 0.f;
#pragma unroll
                    for (int nt = 0; nt < 8; ++nt) {
                        const float v = acc[mt][nt][reg];
                        const unsigned short us = f2us(v);
                        ((unsigned short*)Cp)[(long)gr * HID + nt * 16 + r] = us;
                        const float vr = us2f(us);
                        if (nt < 2)      { s0 = fmaf(vr, aS[nt], s0); d0 = fmaf(vr, aD[nt], d0); }
                        else if (nt < 4) { s1 = fmaf(vr, aS[nt], s1); d1 = fmaf(vr, aD[nt], d1); }
                        else if (nt < 6) { s2 = fmaf(vr, aS[nt], s2); d2 = fmaf(vr, aD[nt], d2); }
                        else             { s3 = fmaf(vr, aS[nt], s3); d3 = fmaf(vr, aD[nt], d3); }
                    }
#pragma unroll
                    for (int o = 1; o < 16; o <<= 1) {
                        s0 += __shfl_xor(s0, o); s1 += __shfl_xor(s1, o);
                        s2 += __shfl_xor(s2, o); s3 += __shfl_xor(s3, o);
                        d0 += __shfl_xor(d0, o); d1 += __shfl_xor(d1, o);
                        d2 += __shfl_xor(d2, o); d3 += __shfl_xor(d3, o);
                    }
                    const int hsel = r & 3;
                    const float sv = hsel == 0 ? s0 : (hsel == 1 ? s1 : (hsel == 2 ? s2 : s3));
                    const float dv = hsel == 0 ? d0 : (hsel == 1 ? d1 : (hsel == 2 ? d2 : d3));
                    if (r < 4)      asrc[(size_t)gr * 4 + hsel] = sv;
                    else if (r < 8) adst[(size_t)gr * 4 + hsel] = dv;
                }
            }
        }
    } else {
        float bb[8];
#pragma unroll
        for (int nt = 0; nt < 8; ++nt) bb[nt] = bias ? ldw(bias, bias_off + nt * 16 + r, bf) : 0.f;

#pragma unroll
        for (int mt = 0; mt < 2; ++mt) {
            const int gr0 = bm + wave * 32 + mt * 16 + quad * 4;
#pragma unroll
            for (int reg = 0; reg < 4; ++reg) {
                const int gr = gr0 + reg;
                if (gr < M) {
#pragma unroll
                    for (int nt = 0; nt < 8; ++nt) {
                        float v = acc[mt][nt][reg] + bb[nt];
                        if (do_relu) v = fmaxf(v, 0.f);
                        const long ci = (long)gr * HID + nt * 16 + r;
                        if (C_BF) ((unsigned short*)Cp)[ci] = f2us(v);
                        else      ((float*)Cp)[ci] = v;
                    }
                }
            }
        }
    }
}

// ---------- GAT aggregate + bias + LN + ReLU + residual ----------
// ONE NODE PER 32-LANE HALF (2 independent nodes per wave, 8 per block).
// Softmax shifted by the SELF-edge score (shift-invariant; self weight == 1).
__global__ __launch_bounds__(256) void gat_kernel(float* __restrict__ h,
                                                  const unsigned short* __restrict__ hp,
                                                  const float* __restrict__ asrc,
                                                  const float* __restrict__ adst,
                                                  const int* __restrict__ row_ptr,
                                                  const int* __restrict__ csr,
                                                  const void* __restrict__ bgat,
                                                  const void* __restrict__ lng,
                                                  const void* __restrict__ lnb, long w_off,
                                                  int N, const int* __restrict__ flagp) {
    __shared__ uint2 ebuf[8][160];
    const int bf = flagp[0];
    const int lane = threadIdx.x & 63;
    const int wslot = threadIdx.x >> 6;
    const int half = lane >> 5;
    const int ll = lane & 31;
    const int head4 = ll >> 3;     // head owning this lane's 4-channel group
    const int c0 = ll << 2;        // channel base 0..124
    const int n = (blockIdx.x << 3) | (wslot << 1) | half;
    if (n >= N) return;

    const int e0 = row_ptr[n], e1 = row_ptr[n + 1];
    const float4 ad4 = *(const float4*)(adst + (size_t)n * 4);
    const float4 as4 = *(const float4*)(asrc + (size_t)n * 4);
    float4 es;
    es.x = lrelu(as4.x + ad4.x); es.y = lrelu(as4.y + ad4.y);
    es.z = lrelu(as4.z + ad4.z); es.w = lrelu(as4.w + ad4.w);

    // self contribution: exp(es - es) == 1
    const uint2 us = *(const uint2*)(hp + (size_t)n * HID + c0);
    float4 acc;
    acc.x = lo2f(us.x); acc.y = hi2f(us.x);
    acc.z = lo2f(us.y); acc.w = hi2f(us.y);

    float4 dnp = make_float4(0.f, 0.f, 0.f, 0.f);  // per-lane denominator partials
    uint2* eb = ebuf[(wslot << 1) | half];

    for (int base = e0; base < e1; base += 32) {
        const int cnt = min(32, e1 - base);
        int s = 0;
        float4 ex4 = make_float4(0.f, 0.f, 0.f, 0.f);
        if (ll < cnt) {
            s = csr[base + ll];
            const float4 a = *(const float4*)(asrc + (size_t)s * 4);
            ex4.x = __expf(lrelu(a.x + ad4.x) - es.x);
            ex4.y = __expf(lrelu(a.y + ad4.y) - es.y);
            ex4.z = __expf(lrelu(a.z + ad4.z) - es.z);
            ex4.w = __expf(lrelu(a.w + ad4.w) - es.w);
            dnp.x += ex4.x; dnp.y += ex4.y; dnp.z += ex4.z; dnp.w += ex4.w;
        }
        const unsigned su = (unsigned)s;
        eb[ll * 5 + 0] = make_uint2(su, __float_as_uint(ex4.x));
        eb[ll * 5 + 1] = make_uint2(su, __float_as_uint(ex4.y));
        eb[ll * 5 + 2] = make_uint2(su, __float_as_uint(ex4.z));
        eb[ll * 5 + 3] = make_uint2(su, __float_as_uint(ex4.w));
        // same-wave LDS RAW: compiler orders via lgkmcnt (writer/reader alias eb)

        float4 aA = make_float4(0.f, 0.f, 0.f, 0.f);
        float4 aB = make_float4(0.f, 0.f, 0.f, 0.f);
        float4 aC = make_float4(0.f, 0.f, 0.f, 0.f);
        float4 aD = make_float4(0.f, 0.f, 0.f, 0.f);
        int i = 0;
#define GAT_EDGE(idx, A)                                                      \
        {                                                                     \
            const uint2 q = eb[(idx) * 5 + head4];                            \
            const uint2 u = *(const uint2*)(hp + (size_t)q.x * HID + c0);     \
            const float wq = __uint_as_float(q.y);                            \
            A.x = fmaf(wq, lo2f(u.x), A.x);                                   \
            A.y = fmaf(wq, hi2f(u.x), A.y);                                   \
            A.z = fmaf(wq, lo2f(u.y), A.z);                                   \
            A.w = fmaf(wq, hi2f(u.y), A.w);                                   \
        }
        for (; i + 4 <= cnt; i += 4) {
            GAT_EDGE(i + 0, aA);
            GAT_EDGE(i + 1, aB);
            GAT_EDGE(i + 2, aC);
            GAT_EDGE(i + 3, aD);
        }
        for (; i < cnt; ++i) GAT_EDGE(i, aA);
#undef GAT_EDGE
        acc.x += (aA.x + aB.x) + (aC.x + aD.x);
        acc.y += (aA.y + aB.y) + (aC.y + aD.y);
        acc.z += (aA.z + aB.z) + (aC.z + aD.z);
        acc.w += (aA.w + aB.w) + (aC.w + aD.w);
    }

    float4 dn;
    dn.x = wsum32(dnp.x) + 1.f;
    dn.y = wsum32(dnp.y) + 1.f;
    dn.z = wsum32(dnp.z) + 1.f;
    dn.w = wsum32(dnp.w) + 1.f;

    const float invd = 1.f / fmaxf(pick4(dn, head4), 1e-16f);
    acc.x *= invd; acc.y *= invd; acc.z *= invd; acc.w *= invd;
    acc.x += ldw(bgat, w_off + c0 + 0, bf);
    acc.y += ldw(bgat, w_off + c0 + 1, bf);
    acc.z += ldw(bgat, w_off + c0 + 2, bf);
    acc.w += ldw(bgat, w_off + c0 + 3, bf);

    // LN over the node's 128 channels (4 per lane across the 32-lane half)
    const float mean = wsum32(acc.x + acc.y + acc.z + acc.w) * (1.f / 128.f);
    const float d0 = acc.x - mean, d1 = acc.y - mean, d2 = acc.z - mean, d3 = acc.w - mean;
    const float var = wsum32(d0 * d0 + d1 * d1 + d2 * d2 + d3 * d3) * (1.f / 128.f);
    const float rstd = rsqrtf(var + LN_EPS);
    float o0 = d0 * rstd * ldw(lng, w_off + c0 + 0, bf) + ldw(lnb, w_off + c0 + 0, bf);
    float o1 = d1 * rstd * ldw(lng, w_off + c0 + 1, bf) + ldw(lnb, w_off + c0 + 1, bf);
    float o2 = d2 * rstd * ldw(lng, w_off + c0 + 2, bf) + ldw(lnb, w_off + c0 + 2, bf);
    float o3 = d3 * rstd * ldw(lng, w_off + c0 + 3, bf) + ldw(lnb, w_off + c0 + 3, bf);
    o0 = fmaxf(o0, 0.f); o1 = fmaxf(o1, 0.f); o2 = fmaxf(o2, 0.f); o3 = fmaxf(o3, 0.f);

    const float4 r = *(const float4*)(h + (size_t)n * HID + c0);
    *(float4*)(h + (size_t)n * HID + c0) = make_float4(o0 + r.x, o1 + r.y, o2 + r.z, o3 + r.w);
}

// ---------- pooling (sorted batch -> contiguous ranges, no atomics) ----------
// 1024 threads (16 waves): 8 row-slices per graph for MLP on the 1-block/CU grid
__global__ __launch_bounds__(1024) void pool_kernel(const float* __restrict__ h, const int* __restrict__ batch,
                                                    void* __restrict__ out, int N,
                                                    const int* __restrict__ flagp) {
    const int g = blockIdx.x;
    int a = 0, b = N;
    while (a < b) { int mid = (a + b) >> 1; if (batch[mid] < g) a = mid + 1; else b = mid; }
    const int lo = a;
    b = N;
    while (a < b) { int mid = (a + b) >> 1; if (batch[mid] <= g) a = mid + 1; else b = mid; }
    const int hi = a;

    const int col = threadIdx.x & 127;
    const int slot = threadIdx.x >> 7;   // 0..7
    float s = 0.f;
    for (int r = lo + slot; r < hi; r += 8) s += h[(size_t)r * HID + col];
    __shared__ float part[8][128];
    part[slot][col] = s;
    __syncthreads();
    if (threadIdx.x < 128) {
        float tot = part[0][threadIdx.x];
#pragma unroll
        for (int p = 1; p < 8; ++p) tot += part[p][threadIdx.x];
        const float v = tot / fmaxf((float)(hi - lo), 1.f);
        if (flagp[0]) ((unsigned short*)out)[g * HID + threadIdx.x] = f2us(v);
        else          ((float*)out)[g * HID + threadIdx.x] = v;
    }
}

// ---------- launch ----------
extern "C" void kernel_launch(void* const* d_in, const int* in_sizes, int n_in,
                              void* d_out, int out_size, void* d_ws, size_t ws_size,
                              hipStream_t stream) {
    const void* x     = d_in[0];
    const void* W_in  = d_in[1];
    const void* b_in  = d_in[2];
    const void* W_gat = d_in[3];
    const void* att_s = d_in[4];
    const void* att_d = d_in[5];
    const void* b_gat = d_in[6];
    const void* ln_g  = d_in[7];
    const void* ln_b  = d_in[8];
    const int* edge_index = (const int*)d_in[9];
    const int* batch      = (const int*)d_in[10];

    const int N = in_sizes[10];
    const int E = in_sizes[9] / 2;
    const int IN_DIM = in_sizes[0] / N;
    const int n_graphs = out_size / HID;

    const int* esrc = edge_index;
    const int* edst = edge_index + E;

    char* w = (char*)d_ws;
    auto carve = [&](size_t bytes) -> void* {
        void* p = (void*)w;
        w += (bytes + 255) & ~(size_t)255;
        return p;
    };
    int* flag             = (int*)carve(256);
    int* row_ptr          = (int*)carve((size_t)(N + 1) * 4);
    int* csr              = (int*)carve((size_t)E * 4);
    float* asrc           = (float*)carve((size_t)N * 4 * 4);
    float* adst           = (float*)carve((size_t)N * 4 * 4);
    int* bucket_cnt       = (int*)carve(512 * 4);
    int* bucket_base      = (int*)carve(513 * 4);
    int* cursor           = (int*)carve(512 * 4);
    unsigned short* Wt_in = (unsigned short*)carve((size_t)HID * IN_DIM * 2);
    unsigned short* Wt_g  = (unsigned short*)carve((size_t)3 * HID * HID * 2);
    float* h              = (float*)carve((size_t)N * HID * 4);
    unsigned short* hp    = (unsigned short*)carve((size_t)N * HID * 2);
    // tmp (E x 8B) aliases h: only live during CSR build, before h is first written
    unsigned long long* tmp = (unsigned long long*)h;
    (void)ws_size; (void)n_in;

    // init: dtype sniff + zero bucket counters
    init_kernel<<<2, 256, 0, stream>>>((const float*)x, flag, bucket_cnt);

    // CSR build via bucket partition (256 dst-nodes per bucket)
    const int nb = (N + 255) >> 8;
    const int ntiles = (E + 4095) / 4096;
    bucket_hist_kernel<<<ntiles, 256, 0, stream>>>(edst, E, nb, bucket_cnt);
    bucket_scan_kernel<<<1, 512, 0, stream>>>(bucket_cnt, bucket_base, cursor, nb, row_ptr, N);
    partition_kernel<<<ntiles, 256, 0, stream>>>(esrc, edst, E, nb, cursor, tmp);
    bucket_sort_kernel<<<nb, 256, 0, stream>>>(tmp, bucket_base, row_ptr, csr, N);

    // weight prep (hoisted; all 3 GAT layers in one dispatch)
    transpose_w_kernel<<<(HID * IN_DIM + 255) / 256, 256, 0, stream>>>(W_in, 0, IN_DIM, Wt_in, flag);
    transpose_wg_kernel<<<(3 * HID * HID + 255) / 256, 256, 0, stream>>>(W_gat, Wt_g, flag);

    // input projection: h = relu(x @ W_in + b_in)
    mfma_gemm_kernel<0, 0><<<(N + 127) / 128, 256, 0, stream>>>(
        x, 1, Wt_in, b_in, 0, h, nullptr, nullptr, 0, nullptr, nullptr, N, IN_DIM, 1, flag);

    for (int l = 0; l < 3; ++l) {
        mfma_gemm_kernel<1, 1><<<(N + 127) / 128, 256, 0, stream>>>(
            h, 0, Wt_g + (size_t)l * HID * HID, nullptr, 0, hp,
            att_s, att_d, (long)l * HID, asrc, adst, N, HID, 0, flag);
        gat_kernel<<<(N + 7) / 8, 256, 0, stream>>>(h, hp, asrc, adst, row_ptr, csr,
                                                    b_gat, ln_g, ln_b, (long)l * HID, N, flag);
    }

    pool_kernel<<<n_graphs, 1024, 0, stream>>>(h, batch, d_out, N, flag);
}